// Round 1
// baseline (625.162 us; speedup 1.0000x reference)
//
#include <hip/hip_runtime.h>
#include <math.h>

#define NN 10000
#define NE 320000
#define NODE_F 64
#define EDGE_F 32
#define HDIM 256
#define HEADS 8
#define LAYERS 6
#define NG 16
#define NPB 2   // nodes per node_kernel block, ONE wave per node, no coupling
#define NOUT 48 // LAYERS*HEADS, interleaved preE layout [NE][48]
#define LOG2E 1.4426950408889634f

typedef __attribute__((ext_vector_type(8))) short short8;
typedef __attribute__((ext_vector_type(4))) float float4v;

// ---------------------------------------------------------------- CSR build
__global__ void count_kernel(const int* __restrict__ dst, int* __restrict__ cnt) {
    int e = blockIdx.x * 256 + threadIdx.x;
    if (e < NE) atomicAdd(&cnt[dst[e]], 1);
}

__global__ void scan_kernel(const int* __restrict__ cnt, int* __restrict__ row_ptr,
                            int* __restrict__ pos) {
    __shared__ int part[1024];
    int t = threadIdx.x;
    const int chunk = (NN + 1023) / 1024;  // 10
    int lo = t * chunk, hi = min(NN, lo + chunk);
    int s = 0;
    for (int i = lo; i < hi; ++i) s += cnt[i];
    part[t] = s;
    __syncthreads();
    for (int off = 1; off < 1024; off <<= 1) {
        int v = (t >= off) ? part[t - off] : 0;
        __syncthreads();
        part[t] += v;
        __syncthreads();
    }
    int base = (t == 0) ? 0 : part[t - 1];
    for (int i = lo; i < hi; ++i) {
        row_ptr[i] = base;
        pos[i] = base;
        base += cnt[i];
    }
    if (t == 1023) row_ptr[NN] = part[1023];
}

// ---------------------------------------------------------------- bf16 helpers
__device__ __forceinline__ ushort f2bf(float f) {
    union { float f; unsigned u; } v; v.f = f;
    unsigned u = v.u;
    return (ushort)((u + 0x7fffu + ((u >> 16) & 1u)) >> 16);
}
__device__ __forceinline__ float bf2f(ushort b) {
    union { unsigned u; float f; } v; v.u = ((unsigned)b) << 16; return v.f;
}

// scatter + permute edge_attr into CSR order as bf16 (64 B contiguous per edge)
__global__ void scatter_kernel(const int* __restrict__ src, const int* __restrict__ dst,
                               const float* __restrict__ edge_attr,
                               int* __restrict__ pos, int* __restrict__ csr_src,
                               ushort* __restrict__ ea_bf) {
    int e = blockIdx.x * 256 + threadIdx.x;
    if (e >= NE) return;
    int d = dst[e];
    int idx = atomicAdd(&pos[d], 1);
    csr_src[idx] = src[e];
    const float4* p = (const float4*)(edge_attr + (size_t)e * EDGE_F);
    uint4* q = (uint4*)(ea_bf + (size_t)idx * EDGE_F);
    #pragma unroll
    for (int i = 0; i < 4; ++i) {
        float4 v0 = p[i * 2], v1 = p[i * 2 + 1];
        uint4 pk;
        pk.x = (unsigned)f2bf(v0.x) | ((unsigned)f2bf(v0.y) << 16);
        pk.y = (unsigned)f2bf(v0.z) | ((unsigned)f2bf(v0.w) << 16);
        pk.z = (unsigned)f2bf(v1.x) | ((unsigned)f2bf(v1.y) << 16);
        pk.w = (unsigned)f2bf(v1.z) | ((unsigned)f2bf(v1.w) << 16);
        q[i] = pk;
    }
}

// ---------------------------------------------------------------- edge-attn weight folding
// Fused v_kernel + we_kernel + bf16 conversion. One block per (layer,head).
// Outputs pre-scaled by LOG2E so downstream softmax uses exp2.
__global__ __launch_bounds__(256) void prep_kernel(const float* __restrict__ att_edge,
                                                   const float* __restrict__ lin_edge_w,
                                                   const float* __restrict__ eew,
                                                   const float* __restrict__ eeb,
                                                   ushort* __restrict__ webbf,
                                                   float* __restrict__ bebuf) {
    int ih = blockIdx.x;            // i*HEADS + h
    int i = ih >> 3, h = ih & 7;
    __shared__ float vsh[HDIM];
    int t = threadIdx.x;
    // v[k] = sum_o att_edge[i,h,o] * lin_edge_w[i, h*32+o, k]
    float s = 0.f;
    const float* ae = att_edge + ih * 32;
    const float* lw = lin_edge_w + ((size_t)i * HDIM + h * 32) * HDIM + t;
    #pragma unroll
    for (int o = 0; o < 32; ++o) s += ae[o] * lw[(size_t)o * HDIM];
    vsh[t] = s;
    __syncthreads();
    if (t < EDGE_F) {
        float acc = 0.f;
        for (int k = 0; k < HDIM; ++k) acc += vsh[k] * eew[k * EDGE_F + t];
        webbf[ih * EDGE_F + t] = f2bf(acc * LOG2E);
    } else if (t == EDGE_F) {
        float acc = 0.f;
        for (int k = 0; k < HDIM; ++k) acc += vsh[k] * eeb[k];
        bebuf[ih] = acc * LOG2E;
    }
}

// ---------------------------------------------------------------- preE via MFMA
// preEb[idx][li*8+h] = ea_bf[idx,:] . we[li*8+h,:] + be[li*8+h]   ([NE][48] bf16, LOG2E-scaled)
__global__ __launch_bounds__(256) void preE_kernel(const ushort* __restrict__ ea_bf,
                                                   const ushort* __restrict__ web,
                                                   const float* __restrict__ be,
                                                   ushort* __restrict__ preEb) {
    int wv = threadIdx.x >> 6, l = threadIdx.x & 63;
    int base = blockIdx.x * 64 + wv * 16;
    int m = l & 15, kq = (l >> 4) * 8;
    short8 afrag = *(const short8*)(ea_bf + (size_t)(base + m) * EDGE_F + kq);
    float4v zero = {0.f, 0.f, 0.f, 0.f};
    float4v acc[3];
    #pragma unroll
    for (int ct = 0; ct < 3; ++ct) {
        short8 bfrag = *(const short8*)(web + (size_t)(ct * 16 + m) * EDGE_F + kq);
        acc[ct] = __builtin_amdgcn_mfma_f32_16x16x32_bf16(afrag, bfrag, zero, 0, 0, 0);
    }
    #pragma unroll
    for (int ct = 0; ct < 3; ++ct) {
        int oc = ct * 16 + m;
        float bv = be[oc];
        #pragma unroll
        for (int r = 0; r < 4; ++r) {
            int row = (l >> 4) * 4 + r;
            preEb[(size_t)(base + row) * NOUT + oc] = f2bf(acc[ct][r] + bv);
        }
    }
}

// preL[l][n][h] = deg>0 ? mean over CSR range of preE : 0 — full 96B row reads
__global__ __launch_bounds__(256) void preL_kernel(const ushort* __restrict__ preEb,
                                                   const int* __restrict__ row_ptr,
                                                   float* __restrict__ preL) {
    int g = threadIdx.x >> 5, c = threadIdx.x & 31;
    int n = blockIdx.x * 8 + g;  // NN % 8 == 0
    int start = row_ptr[n], end = row_ptr[n + 1];
    int deg = end - start;
    float s[NOUT] = {};
    for (int idx = start + c; idx < end; idx += 32) {
        const uint4* row = (const uint4*)(preEb + (size_t)idx * NOUT);
        #pragma unroll
        for (int q = 0; q < 6; ++q) {
            uint4 pk = row[q];
            s[q * 8 + 0] += bf2f((ushort)(pk.x & 0xffff));
            s[q * 8 + 1] += bf2f((ushort)(pk.x >> 16));
            s[q * 8 + 2] += bf2f((ushort)(pk.y & 0xffff));
            s[q * 8 + 3] += bf2f((ushort)(pk.y >> 16));
            s[q * 8 + 4] += bf2f((ushort)(pk.z & 0xffff));
            s[q * 8 + 5] += bf2f((ushort)(pk.z >> 16));
            s[q * 8 + 6] += bf2f((ushort)(pk.w & 0xffff));
            s[q * 8 + 7] += bf2f((ushort)(pk.w >> 16));
        }
    }
    #pragma unroll
    for (int off = 16; off >= 1; off >>= 1)
        #pragma unroll
        for (int h = 0; h < NOUT; ++h) s[h] += __shfl_xor(s[h], off, 32);
    if (c == 0) {
        float invd = deg > 0 ? 1.f / (float)deg : 0.f;
        for (int li = 0; li < LAYERS; ++li) {
            float4* dstp = (float4*)(preL + ((size_t)li * NN + n) * 8);
            dstp[0] = make_float4(s[li * 8 + 0] * invd, s[li * 8 + 1] * invd,
                                  s[li * 8 + 2] * invd, s[li * 8 + 3] * invd);
            dstp[1] = make_float4(s[li * 8 + 4] * invd, s[li * 8 + 5] * invd,
                                  s[li * 8 + 6] * invd, s[li * 8 + 7] * invd);
        }
    }
}

// ---------------------------------------------------------------- f32 -> bf16 (all three buffers)
__global__ void tobf_all_kernel(const float* __restrict__ lin_w, const float* __restrict__ node_w,
                                const float* __restrict__ x, ushort* __restrict__ wbhi,
                                ushort* __restrict__ nwhi, ushort* __restrict__ xhi) {
    const int N1 = LAYERS * HDIM * HDIM;   // 393216
    const int N2 = N1 + HDIM * NODE_F;     // 409600
    const int N3 = N2 + NN * NODE_F;       // 1049600
    int i = blockIdx.x * 256 + threadIdx.x;
    if (i < N1) wbhi[i] = f2bf(lin_w[i]);
    else if (i < N2) nwhi[i - N1] = f2bf(node_w[i - N1]);
    else if (i < N3) xhi[i - N2] = f2bf(x[i - N2]);
}

// ---------------------------------------------------------------- pure-bf16 MFMA GEMM
// C = A_bf . B_bf^T (+bias). If att_s != nullptr, also computes per-row attention
// logit partials a_src/a_dst (LOG2E-scaled) in the epilogue — each 64-col block
// covers exactly 2 complete heads, so no atomics are needed.
__global__ __launch_bounds__(128) void gemm_bf1(const ushort* __restrict__ Ah,
                                                const ushort* __restrict__ Bh,
                                                const float* __restrict__ bias,
                                                float* __restrict__ C,
                                                ushort* __restrict__ Chi,
                                                const float* __restrict__ att_s,
                                                const float* __restrict__ att_d,
                                                float* __restrict__ a_src,
                                                float* __restrict__ a_dst,
                                                int N, int K, int J) {
    __shared__ ushort sAh[64][40], sBh[64][40];
    int nb = blockIdx.y * 64, jb = blockIdx.x * 64;
    int t = threadIdx.x, w = t >> 6, l = t & 63;
    int srow = t >> 1, sq = (t & 1) * 16;
    int fr = l & 15, fq = (l >> 4) * 8;
    float4v acc[2][4] = {};
    for (int kt = 0; kt < K; kt += 32) {
        int gr = nb + srow;
        short8 a0 = {0,0,0,0,0,0,0,0}, a1 = {0,0,0,0,0,0,0,0};
        if (gr < N) {
            const short8* pa = (const short8*)(Ah + (size_t)gr * K + kt + sq);
            a0 = pa[0]; a1 = pa[1];
        }
        *(short8*)&sAh[srow][sq] = a0; *(short8*)&sAh[srow][sq + 8] = a1;
        const short8* pb = (const short8*)(Bh + (size_t)(jb + srow) * K + kt + sq);
        short8 b0 = pb[0], b1 = pb[1];
        *(short8*)&sBh[srow][sq] = b0; *(short8*)&sBh[srow][sq + 8] = b1;
        __syncthreads();
        short8 bh[4];
        #pragma unroll
        for (int nt = 0; nt < 4; ++nt)
            bh[nt] = *(const short8*)&sBh[nt * 16 + fr][fq];
        #pragma unroll
        for (int mt = 0; mt < 2; ++mt) {
            short8 ah = *(const short8*)&sAh[w * 32 + mt * 16 + fr][fq];
            #pragma unroll
            for (int nt = 0; nt < 4; ++nt)
                acc[mt][nt] = __builtin_amdgcn_mfma_f32_16x16x32_bf16(ah, bh[nt], acc[mt][nt], 0, 0, 0);
        }
        __syncthreads();
    }
    #pragma unroll
    for (int mt = 0; mt < 2; ++mt) {
        #pragma unroll
        for (int nt = 0; nt < 4; ++nt) {
            int col = jb + nt * 16 + fr;
            float bv = bias ? bias[col] : 0.f;
            #pragma unroll
            for (int r = 0; r < 4; ++r) {
                int row = nb + w * 32 + mt * 16 + (l >> 4) * 4 + r;
                if (row < N) {
                    float v = acc[mt][nt][r] + bv;
                    if (C) C[(size_t)row * J + col] = v;
                    if (Chi) Chi[(size_t)row * J + col] = f2bf(v);
                }
            }
        }
    }
    if (att_s) {
        // head h covers cols 32h..32h+31; this block's cols jb..jb+63 = heads head0, head0+1
        int head0 = jb >> 5;
        float cs[4], cd[4];
        #pragma unroll
        for (int nt = 0; nt < 4; ++nt) {
            cs[nt] = att_s[jb + nt * 16 + fr] * LOG2E;
            cd[nt] = att_d[jb + nt * 16 + fr] * LOG2E;
        }
        #pragma unroll
        for (int mt = 0; mt < 2; ++mt) {
            #pragma unroll
            for (int r = 0; r < 4; ++r) {
                float s0 = acc[mt][0][r] * cs[0] + acc[mt][1][r] * cs[1];
                float s1 = acc[mt][2][r] * cs[2] + acc[mt][3][r] * cs[3];
                float d0 = acc[mt][0][r] * cd[0] + acc[mt][1][r] * cd[1];
                float d1 = acc[mt][2][r] * cd[2] + acc[mt][3][r] * cd[3];
                #pragma unroll
                for (int off = 8; off >= 1; off >>= 1) {
                    s0 += __shfl_xor(s0, off, 16);
                    s1 += __shfl_xor(s1, off, 16);
                    d0 += __shfl_xor(d0, off, 16);
                    d1 += __shfl_xor(d1, off, 16);
                }
                if (fr == 0) {
                    int row = nb + w * 32 + mt * 16 + (l >> 4) * 4 + r;
                    if (row < N) {
                        a_src[row * 8 + head0]     = s0;
                        a_src[row * 8 + head0 + 1] = s1;
                        a_dst[row * 8 + head0]     = d0;
                        a_dst[row * 8 + head0 + 1] = d1;
                    }
                }
            }
        }
    }
}

__device__ __forceinline__ float gelu_exact(float x) {
    return 0.5f * x * (1.f + erff(x * 0.70710678118654752f));
}

// ---------------------------------------------------------------- fused single-pass node kernel
// No-max softmax (logits pre-scaled by LOG2E -> single v_exp_f32 via exp2f),
// per-lane redundant denominator, aggregate unrolled x8 for gather ILP.
__global__ __launch_bounds__(64 * NPB) void node_kernel(const ushort* __restrict__ xwbf,
                                                  const ushort* __restrict__ pb,
                                                  const float* __restrict__ preL,
                                                  const float* __restrict__ a_src,
                                                  const float* __restrict__ a_dst,
                                                  const int* __restrict__ row_ptr,
                                                  const int* __restrict__ csr_src,
                                                  const float* __restrict__ h_prev,
                                                  float* __restrict__ h_next,
                                                  ushort* __restrict__ hhi,
                                                  const float* __restrict__ cb,
                                                  const float* __restrict__ lg,
                                                  const float* __restrict__ lb, int first) {
    int wv = threadIdx.x >> 6, l = threadIdx.x & 63;
    int n = blockIdx.x * NPB + wv;
    int start = row_ptr[n], end = row_ptr[n + 1];
    int hc = l >> 3;
    float adnh = a_dst[n * 8 + hc];
    const ushort* xb = xwbf + 4 * l;

    float den, acc[4];
    {
        float al = a_src[n * 8 + hc] + adnh + preL[n * 8 + hc];
        al = al > 0.f ? al : 0.2f * al;
        float wself = exp2f(fminf(al, 57.7f));
        den = wself;
        uint2 gs = *(const uint2*)(xb + (size_t)n * HDIM);
        acc[0] = wself * bf2f((ushort)(gs.x & 0xffff));
        acc[1] = wself * bf2f((ushort)(gs.x >> 16));
        acc[2] = wself * bf2f((ushort)(gs.y & 0xffff));
        acc[3] = wself * bf2f((ushort)(gs.y >> 16));
    }
    int idx = start;
    for (; idx + 8 <= end; idx += 8) {
        int sn[8];
        uint2 g[8];
        float p[8], a[8], w8[8];
        #pragma unroll
        for (int j = 0; j < 8; ++j) sn[j] = csr_src[idx + j];
        #pragma unroll
        for (int j = 0; j < 8; ++j) g[j] = *(const uint2*)(xb + (size_t)sn[j] * HDIM);
        #pragma unroll
        for (int j = 0; j < 8; ++j) p[j] = bf2f(pb[(size_t)(idx + j) * NOUT + hc]);
        #pragma unroll
        for (int j = 0; j < 8; ++j) a[j] = a_src[(size_t)sn[j] * 8 + hc] + adnh + p[j];
        #pragma unroll
        for (int j = 0; j < 8; ++j) {
            float t = a[j] > 0.f ? a[j] : 0.2f * a[j];
            w8[j] = exp2f(fminf(t, 57.7f));
        }
        #pragma unroll
        for (int j = 0; j < 8; ++j) {
            den += w8[j];
            acc[0] += w8[j] * bf2f((ushort)(g[j].x & 0xffff));
            acc[1] += w8[j] * bf2f((ushort)(g[j].x >> 16));
            acc[2] += w8[j] * bf2f((ushort)(g[j].y & 0xffff));
            acc[3] += w8[j] * bf2f((ushort)(g[j].y >> 16));
        }
    }
    for (; idx < end; ++idx) {
        int sn = csr_src[idx];
        uint2 g = *(const uint2*)(xb + (size_t)sn * HDIM);
        float a = a_src[(size_t)sn * 8 + hc] + adnh + bf2f(pb[(size_t)idx * NOUT + hc]);
        a = a > 0.f ? a : 0.2f * a;
        float wt = exp2f(fminf(a, 57.7f));
        den += wt;
        acc[0] += wt * bf2f((ushort)(g.x & 0xffff));
        acc[1] += wt * bf2f((ushort)(g.x >> 16));
        acc[2] += wt * bf2f((ushort)(g.y & 0xffff));
        acc[3] += wt * bf2f((ushort)(g.y >> 16));
    }
    float4 cb4 = *(const float4*)(cb + 4 * l);
    float invh = 1.f / (den + 1e-16f);
    acc[0] = acc[0] * invh + cb4.x;
    acc[1] = acc[1] * invh + cb4.y;
    acc[2] = acc[2] * invh + cb4.z;
    acc[3] = acc[3] * invh + cb4.w;

    // LayerNorm over 256 channels
    float part = acc[0] + acc[1] + acc[2] + acc[3];
    #pragma unroll
    for (int off = 32; off >= 1; off >>= 1) part += __shfl_xor(part, off, 64);
    float mu = part * (1.f / 256.f);
    float p2 = 0.f;
    #pragma unroll
    for (int j = 0; j < 4; ++j) {
        float d = acc[j] - mu;
        p2 += d * d;
    }
    #pragma unroll
    for (int off = 32; off >= 1; off >>= 1) p2 += __shfl_xor(p2, off, 64);
    float rstd = rsqrtf(p2 * (1.f / 256.f) + 1e-5f);

    float4 lg4 = *(const float4*)(lg + 4 * l);
    float4 lb4 = *(const float4*)(lb + 4 * l);
    float o4[4];
    float lgv[4] = {lg4.x, lg4.y, lg4.z, lg4.w};
    float lbv[4] = {lb4.x, lb4.y, lb4.z, lb4.w};
    float4 hp = make_float4(0.f, 0.f, 0.f, 0.f);
    if (!first) hp = *(const float4*)(h_prev + (size_t)n * HDIM + 4 * l);
    float hpv[4] = {hp.x, hp.y, hp.z, hp.w};
    #pragma unroll
    for (int j = 0; j < 4; ++j) {
        float y = (acc[j] - mu) * rstd * lgv[j] + lbv[j];
        o4[j] = gelu_exact(y) + hpv[j];
    }
    *(float4*)(h_next + (size_t)n * HDIM + 4 * l) = make_float4(o4[0], o4[1], o4[2], o4[3]);
    uint2 ph;
    ph.x = (unsigned)f2bf(o4[0]) | ((unsigned)f2bf(o4[1]) << 16);
    ph.y = (unsigned)f2bf(o4[2]) | ((unsigned)f2bf(o4[3]) << 16);
    *(uint2*)(hhi + (size_t)n * HDIM + 4 * l) = ph;
}

// ---------------------------------------------------------------- graph readout
__global__ __launch_bounds__(256) void graph_sum_kernel(const float* __restrict__ h,
                                                        const int* __restrict__ batch,
                                                        float* __restrict__ sums) {
    int t = threadIdx.x;
    int n0 = blockIdx.x * 64;
    int n1 = min(NN, n0 + 64);
    float acc = 0.f;
    int cur = batch[n0];
    for (int n = n0; n < n1; ++n) {
        int b = batch[n];
        if (b != cur) {
            atomicAdd(&sums[cur * HDIM + t], acc);
            acc = 0.f;
            cur = b;
        }
        acc += h[(size_t)n * HDIM + t];
    }
    atomicAdd(&sums[cur * HDIM + t], acc);
}

__device__ __forceinline__ int lower_bound_dev(const int* a, int n, int v) {
    int lo = 0, hi = n;
    while (lo < hi) {
        int mid = (lo + hi) >> 1;
        if (a[mid] < v) lo = mid + 1; else hi = mid;
    }
    return lo;
}

// fused 3-layer MLP head: one block per (graph, which)
__global__ __launch_bounds__(256) void mlp_kernel(const float* __restrict__ sums,
                                                  const int* __restrict__ batch,
                                                  const float* __restrict__ pw1,
                                                  const float* __restrict__ pb1,
                                                  const float* __restrict__ pw2,
                                                  const float* __restrict__ pb2,
                                                  const float* __restrict__ pw3,
                                                  const float* __restrict__ pb3,
                                                  const float* __restrict__ mw1,
                                                  const float* __restrict__ mb1,
                                                  const float* __restrict__ mw2,
                                                  const float* __restrict__ mb2,
                                                  const float* __restrict__ mw3,
                                                  const float* __restrict__ mb3,
                                                  float* __restrict__ out) {
    int g = blockIdx.x, which = blockIdx.y;
    const float* w1 = which ? mw1 : pw1; const float* b1 = which ? mb1 : pb1;
    const float* w2 = which ? mw2 : pw2; const float* b2 = which ? mb2 : pb2;
    const float* w3 = which ? mw3 : pw3; const float* b3 = which ? mb3 : pb3;
    __shared__ float xg[512];
    __shared__ float h1[256];
    __shared__ float h2[128];
    __shared__ float cinv_s;
    int t = threadIdx.x;
    if (t == 0) {
        int s0 = lower_bound_dev(batch, NN, g), s1 = lower_bound_dev(batch, NN, g + 1);
        cinv_s = 1.f / fmaxf((float)(s1 - s0), 1.f);
    }
    __syncthreads();
    float sv = sums[g * HDIM + t];
    xg[t] = sv * cinv_s;
    xg[256 + t] = sv;
    __syncthreads();
    // layer 1: row t, dot 512
    {
        const float* wr = w1 + (size_t)t * 512;
        float acc = 0.f;
        #pragma unroll 8
        for (int k = 0; k < 512; k += 4) {
            float4 wv = *(const float4*)(wr + k);
            acc += wv.x * xg[k] + wv.y * xg[k + 1] + wv.z * xg[k + 2] + wv.w * xg[k + 3];
        }
        h1[t] = gelu_exact(acc + b1[t]);
    }
    __syncthreads();
    // layer 2: row t>>1, 2 threads per row (halves of dot 256)
    {
        int row = t >> 1, hf = t & 1;
        const float* wr = w2 + (size_t)row * 256 + hf * 128;
        const float* hx = h1 + hf * 128;
        float acc = 0.f;
        #pragma unroll 8
        for (int k = 0; k < 128; k += 4) {
            float4 wv = *(const float4*)(wr + k);
            acc += wv.x * hx[k] + wv.y * hx[k + 1] + wv.z * hx[k + 2] + wv.w * hx[k + 3];
        }
        acc += __shfl_xor(acc, 1, 64);
        if (hf == 0) h2[row] = gelu_exact(acc + b2[row]);
    }
    __syncthreads();
    // layer 3 + sigmoid: wave 0
    if (t < 64) {
        float v0 = h2[t], v1 = h2[64 + t];
        #pragma unroll
        for (int o = 0; o < 3; ++o) {
            float p = w3[o * 128 + t] * v0 + w3[o * 128 + 64 + t] * v1;
            #pragma unroll
            for (int off = 32; off >= 1; off >>= 1) p += __shfl_xor(p, off, 64);
            if (t == 0) out[which * (NG * 3) + g * 3 + o] = 1.f / (1.f + expf(-(p + b3[o])));
        }
    }
}

// ---------------------------------------------------------------- launch
extern "C" void kernel_launch(void* const* d_in, const int* in_sizes, int n_in, void* d_out,
                              int out_size, void* d_ws, size_t ws_size, hipStream_t stream) {
    const float* x         = (const float*)d_in[0];
    const int*   ei        = (const int*)d_in[1];
    const int*   src       = ei;
    const int*   dst       = ei + NE;
    const float* edge_attr = (const float*)d_in[2];
    const int*   batch     = (const int*)d_in[3];
    const float* node_w    = (const float*)d_in[4];
    const float* node_b    = (const float*)d_in[5];
    const float* eew       = (const float*)d_in[6];
    const float* eeb       = (const float*)d_in[7];
    const float* lin_w     = (const float*)d_in[8];
    const float* att_src   = (const float*)d_in[9];
    const float* att_dst   = (const float*)d_in[10];
    const float* att_edge  = (const float*)d_in[11];
    const float* lin_edge_w= (const float*)d_in[12];
    const float* conv_b    = (const float*)d_in[13];
    const float* ln_g      = (const float*)d_in[14];
    const float* ln_b      = (const float*)d_in[15];
    const float* pw1 = (const float*)d_in[16]; const float* pb1 = (const float*)d_in[17];
    const float* pw2 = (const float*)d_in[18]; const float* pb2 = (const float*)d_in[19];
    const float* pw3 = (const float*)d_in[20]; const float* pb3 = (const float*)d_in[21];
    const float* mw1 = (const float*)d_in[22]; const float* mb1 = (const float*)d_in[23];
    const float* mw2 = (const float*)d_in[24]; const float* mb2 = (const float*)d_in[25];
    const float* mw3 = (const float*)d_in[26]; const float* mb3 = (const float*)d_in[27];
    float* out = (float*)d_out;

    float* wsf = (float*)d_ws;
    float* hA        = wsf; wsf += (size_t)NN * HDIM;
    float* hB        = wsf; wsf += (size_t)NN * HDIM;
    float* preL      = wsf; wsf += (size_t)LAYERS * NN * 8;
    float* a_src     = wsf; wsf += (size_t)NN * HEADS;
    float* a_dst     = wsf; wsf += (size_t)NN * HEADS;
    float* bebuf     = wsf; wsf += 64;
    ushort* ubuf = (ushort*)wsf;
    ushort* ea_bf = ubuf; ubuf += (size_t)NE * EDGE_F;
    ushort* preEb = ubuf; ubuf += (size_t)NE * NOUT;
    ushort* webbf = ubuf; ubuf += (size_t)NOUT * EDGE_F;
    ushort* hhi  = ubuf; ubuf += (size_t)NN * HDIM;
    ushort* xwbf = ubuf; ubuf += (size_t)NN * HDIM;
    ushort* wbhi = ubuf; ubuf += (size_t)LAYERS * HDIM * HDIM;
    ushort* xhi  = ubuf; ubuf += (size_t)NN * NODE_F;
    ushort* nwhi = ubuf; ubuf += (size_t)HDIM * NODE_F;
    int* ibuf    = (int*)ubuf;
    int* cnt     = ibuf; ibuf += NN + 16;
    float* sums  = (float*)ibuf; ibuf += NG * HDIM;  // adjacent to cnt -> one memset
    int* row_ptr = ibuf; ibuf += NN + 16;
    int* pos     = ibuf; ibuf += NN + 16;
    int* csr_src = ibuf; ibuf += NE;

    // CSR build (+ permute edge_attr to CSR order, bf16); one memset covers cnt+sums
    hipMemsetAsync(cnt, 0, (NN + 16 + NG * HDIM) * sizeof(int), stream);
    count_kernel<<<(NE + 255) / 256, 256, 0, stream>>>(dst, cnt);
    scan_kernel<<<1, 1024, 0, stream>>>(cnt, row_ptr, pos);
    scatter_kernel<<<(NE + 255) / 256, 256, 0, stream>>>(src, dst, edge_attr, pos, csr_src,
                                                         ea_bf);

    // fold edge-attention weights (LOG2E-scaled); preE via MFMA; preL = mean over CSR range
    prep_kernel<<<LAYERS * HEADS, 256, 0, stream>>>(att_edge, lin_edge_w, eew, eeb, webbf, bebuf);
    preE_kernel<<<NE / 64, 256, 0, stream>>>(ea_bf, webbf, bebuf, preEb);
    preL_kernel<<<NN / 8, 256, 0, stream>>>(preEb, row_ptr, preL);

    // GEMM operand prep: everything bf16 (pure-bf16 GEMM), one fused conversion kernel
    {
        const int total = LAYERS * HDIM * HDIM + HDIM * NODE_F + NN * NODE_F;
        tobf_all_kernel<<<(total + 255) / 256, 256, 0, stream>>>(lin_w, node_w, x,
                                                                 wbhi, nwhi, xhi);
    }

    // node embedding: hA = x @ node_w.T + node_b  (f32 + bf16)
    {
        dim3 grid(HDIM / 64, (NN + 63) / 64);
        gemm_bf1<<<grid, 128, 0, stream>>>(xhi, nwhi, node_b, hA, hhi,
                                           nullptr, nullptr, nullptr, nullptr,
                                           NN, NODE_F, HDIM);
    }

    float* cur = hA;
    float* nxt = hB;
    for (int i = 0; i < LAYERS; ++i) {
        dim3 grid(HDIM / 64, (NN + 63) / 64);
        // layer GEMM writes bf16 xwbf AND the fused a_src/a_dst epilogue
        gemm_bf1<<<grid, 128, 0, stream>>>(hhi, wbhi + (size_t)i * HDIM * HDIM, nullptr,
                                           nullptr, xwbf,
                                           att_src + i * HEADS * 32, att_dst + i * HEADS * 32,
                                           a_src, a_dst, NN, HDIM, HDIM);
        node_kernel<<<NN / NPB, 64 * NPB, 0, stream>>>(
            xwbf, preEb + i * 8, preL + (size_t)i * NN * 8, a_src, a_dst,
            row_ptr, csr_src, cur, nxt, hhi, conv_b + i * HDIM, ln_g + i * HDIM,
            ln_b + i * HDIM, i == 0 ? 1 : 0);
        float* tmp = cur; cur = nxt; nxt = tmp;
    }

    graph_sum_kernel<<<(NN + 63) / 64, 256, 0, stream>>>(cur, batch, sums);
    {
        dim3 gm(NG, 2);
        mlp_kernel<<<gm, 256, 0, stream>>>(sums, batch, pw1, pb1, pw2, pb2, pw3, pb3,
                                           mw1, mb1, mw2, mb2, mw3, mb3, out);
    }
}

// Round 2
// 542.518 us; speedup vs baseline: 1.1523x; 1.1523x over previous
//
#include <hip/hip_runtime.h>
#include <math.h>

#define NN 10000
#define NE 320000
#define NODE_F 64
#define EDGE_F 32
#define HDIM 256
#define HEADS 8
#define LAYERS 6
#define NG 16
#define NPB 2   // nodes per node_kernel block, ONE wave per node, no coupling
#define NOUT 48 // LAYERS*HEADS
#define LOG2E 1.4426950408889634f

typedef __attribute__((ext_vector_type(8))) short short8;
typedef __attribute__((ext_vector_type(4))) float float4v;
typedef __attribute__((ext_vector_type(2))) float floatx2;

// ---------------------------------------------------------------- CSR build
__global__ void count_kernel(const int* __restrict__ dst, int* __restrict__ cnt) {
    int e = blockIdx.x * 256 + threadIdx.x;
    if (e < NE) atomicAdd(&cnt[dst[e]], 1);
}

__global__ void scan_kernel(const int* __restrict__ cnt, int* __restrict__ row_ptr,
                            int* __restrict__ pos) {
    __shared__ int part[1024];
    int t = threadIdx.x;
    const int chunk = (NN + 1023) / 1024;  // 10
    int lo = t * chunk, hi = min(NN, lo + chunk);
    int s = 0;
    for (int i = lo; i < hi; ++i) s += cnt[i];
    part[t] = s;
    __syncthreads();
    for (int off = 1; off < 1024; off <<= 1) {
        int v = (t >= off) ? part[t - off] : 0;
        __syncthreads();
        part[t] += v;
        __syncthreads();
    }
    int base = (t == 0) ? 0 : part[t - 1];
    for (int i = lo; i < hi; ++i) {
        row_ptr[i] = base;
        pos[i] = base;
        base += cnt[i];
    }
    if (t == 1023) row_ptr[NN] = part[1023];
}

// ---------------------------------------------------------------- bf16 helpers
__device__ __forceinline__ ushort f2bf(float f) {
    union { float f; unsigned u; } v; v.f = f;
    unsigned u = v.u;
    return (ushort)((u + 0x7fffu + ((u >> 16) & 1u)) >> 16);
}
__device__ __forceinline__ float bf2f(ushort b) {
    union { unsigned u; float f; } v; v.u = ((unsigned)b) << 16; return v.f;
}

// scatter + permute edge_attr into CSR order as bf16 (64 B contiguous per edge)
__global__ void scatter_kernel(const int* __restrict__ src, const int* __restrict__ dst,
                               const float* __restrict__ edge_attr,
                               int* __restrict__ pos, int* __restrict__ csr_src,
                               ushort* __restrict__ ea_bf) {
    int e = blockIdx.x * 256 + threadIdx.x;
    if (e >= NE) return;
    int d = dst[e];
    int idx = atomicAdd(&pos[d], 1);
    csr_src[idx] = src[e];
    const float4* p = (const float4*)(edge_attr + (size_t)e * EDGE_F);
    uint4* q = (uint4*)(ea_bf + (size_t)idx * EDGE_F);
    #pragma unroll
    for (int i = 0; i < 4; ++i) {
        float4 v0 = p[i * 2], v1 = p[i * 2 + 1];
        uint4 pk;
        pk.x = (unsigned)f2bf(v0.x) | ((unsigned)f2bf(v0.y) << 16);
        pk.y = (unsigned)f2bf(v0.z) | ((unsigned)f2bf(v0.w) << 16);
        pk.z = (unsigned)f2bf(v1.x) | ((unsigned)f2bf(v1.y) << 16);
        pk.w = (unsigned)f2bf(v1.z) | ((unsigned)f2bf(v1.w) << 16);
        q[i] = pk;
    }
}

// ---------------------------------------------------------------- edge-attn weight folding
// Fused fold + bf16 conversion, LOG2E-scaled so downstream softmax uses exp2.
__global__ __launch_bounds__(256) void prep_kernel(const float* __restrict__ att_edge,
                                                   const float* __restrict__ lin_edge_w,
                                                   const float* __restrict__ eew,
                                                   const float* __restrict__ eeb,
                                                   ushort* __restrict__ webbf,
                                                   float* __restrict__ bebuf) {
    int ih = blockIdx.x;            // i*HEADS + h
    int i = ih >> 3, h = ih & 7;
    __shared__ float vsh[HDIM];
    int t = threadIdx.x;
    float s = 0.f;
    const float* ae = att_edge + ih * 32;
    const float* lw = lin_edge_w + ((size_t)i * HDIM + h * 32) * HDIM + t;
    #pragma unroll
    for (int o = 0; o < 32; ++o) s += ae[o] * lw[(size_t)o * HDIM];
    vsh[t] = s;
    __syncthreads();
    if (t < EDGE_F) {
        float acc = 0.f;
        for (int k = 0; k < HDIM; ++k) acc += vsh[k] * eew[k * EDGE_F + t];
        webbf[ih * EDGE_F + t] = f2bf(acc * LOG2E);
    } else if (t == EDGE_F) {
        float acc = 0.f;
        for (int k = 0; k < HDIM; ++k) acc += vsh[k] * eeb[k];
        bebuf[ih] = acc * LOG2E;
    }
}

// ---------------------------------------------------------------- preE via MFMA
// Split layout: preEb[li][edge][h]  ([LAYERS][NE][8] bf16, LOG2E-scaled)
__global__ __launch_bounds__(256) void preE_kernel(const ushort* __restrict__ ea_bf,
                                                   const ushort* __restrict__ web,
                                                   const float* __restrict__ be,
                                                   ushort* __restrict__ preEb) {
    int wv = threadIdx.x >> 6, l = threadIdx.x & 63;
    int base = blockIdx.x * 64 + wv * 16;
    int m = l & 15, kq = (l >> 4) * 8;
    short8 afrag = *(const short8*)(ea_bf + (size_t)(base + m) * EDGE_F + kq);
    float4v zero = {0.f, 0.f, 0.f, 0.f};
    float4v acc[3];
    #pragma unroll
    for (int ct = 0; ct < 3; ++ct) {
        short8 bfrag = *(const short8*)(web + (size_t)(ct * 16 + m) * EDGE_F + kq);
        acc[ct] = __builtin_amdgcn_mfma_f32_16x16x32_bf16(afrag, bfrag, zero, 0, 0, 0);
    }
    #pragma unroll
    for (int ct = 0; ct < 3; ++ct) {
        int oc = ct * 16 + m;
        int li = oc >> 3, hh = oc & 7;
        float bv = be[oc];
        #pragma unroll
        for (int r = 0; r < 4; ++r) {
            int row = (l >> 4) * 4 + r;
            preEb[(size_t)li * NE * 8 + (size_t)(base + row) * 8 + hh] = f2bf(acc[ct][r] + bv);
        }
    }
}

// preL[l][n][h] = deg>0 ? mean over CSR range of preE : 0 — per-layer 16B contiguous reads
__global__ __launch_bounds__(256) void preL_kernel(const ushort* __restrict__ preEb,
                                                   const int* __restrict__ row_ptr,
                                                   float* __restrict__ preL) {
    int g = threadIdx.x >> 5, c = threadIdx.x & 31;
    int n = blockIdx.x * 8 + g;  // NN % 8 == 0
    int start = row_ptr[n], end = row_ptr[n + 1];
    int deg = end - start;
    float s[NOUT] = {};
    for (int idx = start + c; idx < end; idx += 32) {
        #pragma unroll
        for (int li = 0; li < LAYERS; ++li) {
            uint4 pk = *(const uint4*)(preEb + (size_t)li * NE * 8 + (size_t)idx * 8);
            s[li * 8 + 0] += bf2f((ushort)(pk.x & 0xffff));
            s[li * 8 + 1] += bf2f((ushort)(pk.x >> 16));
            s[li * 8 + 2] += bf2f((ushort)(pk.y & 0xffff));
            s[li * 8 + 3] += bf2f((ushort)(pk.y >> 16));
            s[li * 8 + 4] += bf2f((ushort)(pk.z & 0xffff));
            s[li * 8 + 5] += bf2f((ushort)(pk.z >> 16));
            s[li * 8 + 6] += bf2f((ushort)(pk.w & 0xffff));
            s[li * 8 + 7] += bf2f((ushort)(pk.w >> 16));
        }
    }
    #pragma unroll
    for (int off = 16; off >= 1; off >>= 1)
        #pragma unroll
        for (int h = 0; h < NOUT; ++h) s[h] += __shfl_xor(s[h], off, 32);
    if (c == 0) {
        float invd = deg > 0 ? 1.f / (float)deg : 0.f;
        for (int li = 0; li < LAYERS; ++li) {
            float4* dstp = (float4*)(preL + ((size_t)li * NN + n) * 8);
            dstp[0] = make_float4(s[li * 8 + 0] * invd, s[li * 8 + 1] * invd,
                                  s[li * 8 + 2] * invd, s[li * 8 + 3] * invd);
            dstp[1] = make_float4(s[li * 8 + 4] * invd, s[li * 8 + 5] * invd,
                                  s[li * 8 + 6] * invd, s[li * 8 + 7] * invd);
        }
    }
}

// ---------------------------------------------------------------- f32 -> bf16 (all three buffers)
__global__ void tobf_all_kernel(const float* __restrict__ lin_w, const float* __restrict__ node_w,
                                const float* __restrict__ x, ushort* __restrict__ wbhi,
                                ushort* __restrict__ nwhi, ushort* __restrict__ xhi) {
    const int N1 = LAYERS * HDIM * HDIM;   // 393216
    const int N2 = N1 + HDIM * NODE_F;     // 409600
    const int N3 = N2 + NN * NODE_F;       // 1049600
    int i = blockIdx.x * 256 + threadIdx.x;
    if (i < N1) wbhi[i] = f2bf(lin_w[i]);
    else if (i < N2) nwhi[i - N1] = f2bf(node_w[i - N1]);
    else if (i < N3) xhi[i - N2] = f2bf(x[i - N2]);
}

// ---------------------------------------------------------------- pure-bf16 MFMA GEMM
// C = A_bf . B_bf^T (+bias). Optional outputs: f32 C, bf16 Chi, fp8-e4m3 Cf8.
// If att_s != nullptr, also computes per-row attention logit partials a_src/a_dst
// (LOG2E-scaled) from the exact f32 accumulators — each 64-col block covers
// exactly 2 complete heads, so no atomics are needed.
__global__ __launch_bounds__(128) void gemm_bf1(const ushort* __restrict__ Ah,
                                                const ushort* __restrict__ Bh,
                                                const float* __restrict__ bias,
                                                float* __restrict__ C,
                                                ushort* __restrict__ Chi,
                                                unsigned char* __restrict__ Cf8,
                                                const float* __restrict__ att_s,
                                                const float* __restrict__ att_d,
                                                float* __restrict__ a_src,
                                                float* __restrict__ a_dst,
                                                int N, int K, int J) {
    __shared__ ushort sAh[64][40], sBh[64][40];
    int nb = blockIdx.y * 64, jb = blockIdx.x * 64;
    int t = threadIdx.x, w = t >> 6, l = t & 63;
    int srow = t >> 1, sq = (t & 1) * 16;
    int fr = l & 15, fq = (l >> 4) * 8;
    float4v acc[2][4] = {};
    for (int kt = 0; kt < K; kt += 32) {
        int gr = nb + srow;
        short8 a0 = {0,0,0,0,0,0,0,0}, a1 = {0,0,0,0,0,0,0,0};
        if (gr < N) {
            const short8* pa = (const short8*)(Ah + (size_t)gr * K + kt + sq);
            a0 = pa[0]; a1 = pa[1];
        }
        *(short8*)&sAh[srow][sq] = a0; *(short8*)&sAh[srow][sq + 8] = a1;
        const short8* pb = (const short8*)(Bh + (size_t)(jb + srow) * K + kt + sq);
        short8 b0 = pb[0], b1 = pb[1];
        *(short8*)&sBh[srow][sq] = b0; *(short8*)&sBh[srow][sq + 8] = b1;
        __syncthreads();
        short8 bh[4];
        #pragma unroll
        for (int nt = 0; nt < 4; ++nt)
            bh[nt] = *(const short8*)&sBh[nt * 16 + fr][fq];
        #pragma unroll
        for (int mt = 0; mt < 2; ++mt) {
            short8 ah = *(const short8*)&sAh[w * 32 + mt * 16 + fr][fq];
            #pragma unroll
            for (int nt = 0; nt < 4; ++nt)
                acc[mt][nt] = __builtin_amdgcn_mfma_f32_16x16x32_bf16(ah, bh[nt], acc[mt][nt], 0, 0, 0);
        }
        __syncthreads();
    }
    #pragma unroll
    for (int mt = 0; mt < 2; ++mt) {
        #pragma unroll
        for (int nt = 0; nt < 4; ++nt) {
            int col = jb + nt * 16 + fr;
            float bv = bias ? bias[col] : 0.f;
            #pragma unroll
            for (int r = 0; r < 4; ++r) {
                int row = nb + w * 32 + mt * 16 + (l >> 4) * 4 + r;
                if (row < N) {
                    float v = acc[mt][nt][r] + bv;
                    if (C) C[(size_t)row * J + col] = v;
                    if (Chi) Chi[(size_t)row * J + col] = f2bf(v);
                    if (Cf8) {
                        int pk8 = __builtin_amdgcn_cvt_pk_fp8_f32(v, v, 0, false);
                        Cf8[(size_t)row * J + col] = (unsigned char)(pk8 & 0xff);
                    }
                }
            }
        }
    }
    if (att_s) {
        int head0 = jb >> 5;
        float cs[4], cd[4];
        #pragma unroll
        for (int nt = 0; nt < 4; ++nt) {
            cs[nt] = att_s[jb + nt * 16 + fr] * LOG2E;
            cd[nt] = att_d[jb + nt * 16 + fr] * LOG2E;
        }
        #pragma unroll
        for (int mt = 0; mt < 2; ++mt) {
            #pragma unroll
            for (int r = 0; r < 4; ++r) {
                float s0 = acc[mt][0][r] * cs[0] + acc[mt][1][r] * cs[1];
                float s1 = acc[mt][2][r] * cs[2] + acc[mt][3][r] * cs[3];
                float d0 = acc[mt][0][r] * cd[0] + acc[mt][1][r] * cd[1];
                float d1 = acc[mt][2][r] * cd[2] + acc[mt][3][r] * cd[3];
                #pragma unroll
                for (int off = 8; off >= 1; off >>= 1) {
                    s0 += __shfl_xor(s0, off, 16);
                    s1 += __shfl_xor(s1, off, 16);
                    d0 += __shfl_xor(d0, off, 16);
                    d1 += __shfl_xor(d1, off, 16);
                }
                if (fr == 0) {
                    int row = nb + w * 32 + mt * 16 + (l >> 4) * 4 + r;
                    if (row < N) {
                        a_src[row * 8 + head0]     = s0;
                        a_src[row * 8 + head0 + 1] = s1;
                        a_dst[row * 8 + head0]     = d0;
                        a_dst[row * 8 + head0 + 1] = d1;
                    }
                }
            }
        }
    }
}

__device__ __forceinline__ float gelu_exact(float x) {
    return 0.5f * x * (1.f + erff(x * 0.70710678118654752f));
}

// ---------------------------------------------------------------- fused single-pass node kernel
// fp8-e4m3 message table (2.56 MB, per-XCD-L2-resident), no-max exp2 softmax,
// per-lane redundant denominator, aggregate unrolled x8 for gather ILP.
__global__ __launch_bounds__(64 * NPB) void node_kernel(const unsigned char* __restrict__ xwf8,
                                                  const ushort* __restrict__ pb,
                                                  const float* __restrict__ preL,
                                                  const float* __restrict__ a_src,
                                                  const float* __restrict__ a_dst,
                                                  const int* __restrict__ row_ptr,
                                                  const int* __restrict__ csr_src,
                                                  const float* __restrict__ h_prev,
                                                  float* __restrict__ h_next,
                                                  ushort* __restrict__ hhi,
                                                  const float* __restrict__ cb,
                                                  const float* __restrict__ lg,
                                                  const float* __restrict__ lb, int first) {
    int wv = threadIdx.x >> 6, l = threadIdx.x & 63;
    int n = blockIdx.x * NPB + wv;
    int start = row_ptr[n], end = row_ptr[n + 1];
    int hc = l >> 3;
    float adnh = a_dst[n * 8 + hc];
    const unsigned char* xb = xwf8 + 4 * l;

    float den, acc[4];
    {
        float al = a_src[n * 8 + hc] + adnh + preL[n * 8 + hc];
        al = fminf(fmaxf(al, 0.2f * al), 57.7f);
        float wself = exp2f(al);
        den = wself;
        unsigned gs = *(const unsigned*)(xb + (size_t)n * HDIM);
        floatx2 lo = __builtin_amdgcn_cvt_pk_f32_fp8(gs, false);
        floatx2 hi = __builtin_amdgcn_cvt_pk_f32_fp8(gs, true);
        acc[0] = wself * lo.x;
        acc[1] = wself * lo.y;
        acc[2] = wself * hi.x;
        acc[3] = wself * hi.y;
    }
    int idx = start;
    for (; idx + 8 <= end; idx += 8) {
        int sn[8];
        unsigned g[8];
        float p[8], a[8], w8[8];
        #pragma unroll
        for (int j = 0; j < 8; ++j) sn[j] = csr_src[idx + j];
        #pragma unroll
        for (int j = 0; j < 8; ++j) g[j] = *(const unsigned*)(xb + (size_t)sn[j] * HDIM);
        #pragma unroll
        for (int j = 0; j < 8; ++j) p[j] = bf2f(pb[(size_t)(idx + j) * 8 + hc]);
        #pragma unroll
        for (int j = 0; j < 8; ++j) a[j] = a_src[(size_t)sn[j] * 8 + hc] + adnh + p[j];
        #pragma unroll
        for (int j = 0; j < 8; ++j)
            w8[j] = exp2f(fminf(fmaxf(a[j], 0.2f * a[j]), 57.7f));
        #pragma unroll
        for (int j = 0; j < 8; ++j) {
            floatx2 lo = __builtin_amdgcn_cvt_pk_f32_fp8(g[j], false);
            floatx2 hi = __builtin_amdgcn_cvt_pk_f32_fp8(g[j], true);
            den += w8[j];
            acc[0] += w8[j] * lo.x;
            acc[1] += w8[j] * lo.y;
            acc[2] += w8[j] * hi.x;
            acc[3] += w8[j] * hi.y;
        }
    }
    for (; idx < end; ++idx) {
        int sn = csr_src[idx];
        unsigned g = *(const unsigned*)(xb + (size_t)sn * HDIM);
        float a = a_src[(size_t)sn * 8 + hc] + adnh + bf2f(pb[(size_t)idx * 8 + hc]);
        float wt = exp2f(fminf(fmaxf(a, 0.2f * a), 57.7f));
        floatx2 lo = __builtin_amdgcn_cvt_pk_f32_fp8(g, false);
        floatx2 hi = __builtin_amdgcn_cvt_pk_f32_fp8(g, true);
        den += wt;
        acc[0] += wt * lo.x;
        acc[1] += wt * lo.y;
        acc[2] += wt * hi.x;
        acc[3] += wt * hi.y;
    }
    float4 cb4 = *(const float4*)(cb + 4 * l);
    float invh = 1.f / (den + 1e-16f);
    acc[0] = acc[0] * invh + cb4.x;
    acc[1] = acc[1] * invh + cb4.y;
    acc[2] = acc[2] * invh + cb4.z;
    acc[3] = acc[3] * invh + cb4.w;

    // LayerNorm over 256 channels
    float part = acc[0] + acc[1] + acc[2] + acc[3];
    #pragma unroll
    for (int off = 32; off >= 1; off >>= 1) part += __shfl_xor(part, off, 64);
    float mu = part * (1.f / 256.f);
    float p2 = 0.f;
    #pragma unroll
    for (int j = 0; j < 4; ++j) {
        float d = acc[j] - mu;
        p2 += d * d;
    }
    #pragma unroll
    for (int off = 32; off >= 1; off >>= 1) p2 += __shfl_xor(p2, off, 64);
    float rstd = rsqrtf(p2 * (1.f / 256.f) + 1e-5f);

    float4 lg4 = *(const float4*)(lg + 4 * l);
    float4 lb4 = *(const float4*)(lb + 4 * l);
    float o4[4];
    float lgv[4] = {lg4.x, lg4.y, lg4.z, lg4.w};
    float lbv[4] = {lb4.x, lb4.y, lb4.z, lb4.w};
    float4 hp = make_float4(0.f, 0.f, 0.f, 0.f);
    if (!first) hp = *(const float4*)(h_prev + (size_t)n * HDIM + 4 * l);
    float hpv[4] = {hp.x, hp.y, hp.z, hp.w};
    #pragma unroll
    for (int j = 0; j < 4; ++j) {
        float y = (acc[j] - mu) * rstd * lgv[j] + lbv[j];
        o4[j] = gelu_exact(y) + hpv[j];
    }
    *(float4*)(h_next + (size_t)n * HDIM + 4 * l) = make_float4(o4[0], o4[1], o4[2], o4[3]);
    if (hhi) {
        uint2 ph;
        ph.x = (unsigned)f2bf(o4[0]) | ((unsigned)f2bf(o4[1]) << 16);
        ph.y = (unsigned)f2bf(o4[2]) | ((unsigned)f2bf(o4[3]) << 16);
        *(uint2*)(hhi + (size_t)n * HDIM + 4 * l) = ph;
    }
}

// ---------------------------------------------------------------- graph readout
__global__ __launch_bounds__(256) void graph_sum_kernel(const float* __restrict__ h,
                                                        const int* __restrict__ batch,
                                                        float* __restrict__ sums) {
    int t = threadIdx.x;
    int n0 = blockIdx.x * 64;
    int n1 = min(NN, n0 + 64);
    float acc = 0.f;
    int cur = batch[n0];
    for (int n = n0; n < n1; ++n) {
        int b = batch[n];
        if (b != cur) {
            atomicAdd(&sums[cur * HDIM + t], acc);
            acc = 0.f;
            cur = b;
        }
        acc += h[(size_t)n * HDIM + t];
    }
    atomicAdd(&sums[cur * HDIM + t], acc);
}

__device__ __forceinline__ int lower_bound_dev(const int* a, int n, int v) {
    int lo = 0, hi = n;
    while (lo < hi) {
        int mid = (lo + hi) >> 1;
        if (a[mid] < v) lo = mid + 1; else hi = mid;
    }
    return lo;
}

// fused 3-layer MLP head: one block per (graph, which)
__global__ __launch_bounds__(256) void mlp_kernel(const float* __restrict__ sums,
                                                  const int* __restrict__ batch,
                                                  const float* __restrict__ pw1,
                                                  const float* __restrict__ pb1,
                                                  const float* __restrict__ pw2,
                                                  const float* __restrict__ pb2,
                                                  const float* __restrict__ pw3,
                                                  const float* __restrict__ pb3,
                                                  const float* __restrict__ mw1,
                                                  const float* __restrict__ mb1,
                                                  const float* __restrict__ mw2,
                                                  const float* __restrict__ mb2,
                                                  const float* __restrict__ mw3,
                                                  const float* __restrict__ mb3,
                                                  float* __restrict__ out) {
    int g = blockIdx.x, which = blockIdx.y;
    const float* w1 = which ? mw1 : pw1; const float* b1 = which ? mb1 : pb1;
    const float* w2 = which ? mw2 : pw2; const float* b2 = which ? mb2 : pb2;
    const float* w3 = which ? mw3 : pw3; const float* b3 = which ? mb3 : pb3;
    __shared__ float xg[512];
    __shared__ float h1[256];
    __shared__ float h2[128];
    __shared__ float cinv_s;
    int t = threadIdx.x;
    if (t == 0) {
        int s0 = lower_bound_dev(batch, NN, g), s1 = lower_bound_dev(batch, NN, g + 1);
        cinv_s = 1.f / fmaxf((float)(s1 - s0), 1.f);
    }
    __syncthreads();
    float sv = sums[g * HDIM + t];
    xg[t] = sv * cinv_s;
    xg[256 + t] = sv;
    __syncthreads();
    {
        const float* wr = w1 + (size_t)t * 512;
        float acc = 0.f;
        #pragma unroll 8
        for (int k = 0; k < 512; k += 4) {
            float4 wv = *(const float4*)(wr + k);
            acc += wv.x * xg[k] + wv.y * xg[k + 1] + wv.z * xg[k + 2] + wv.w * xg[k + 3];
        }
        h1[t] = gelu_exact(acc + b1[t]);
    }
    __syncthreads();
    {
        int row = t >> 1, hf = t & 1;
        const float* wr = w2 + (size_t)row * 256 + hf * 128;
        const float* hx = h1 + hf * 128;
        float acc = 0.f;
        #pragma unroll 8
        for (int k = 0; k < 128; k += 4) {
            float4 wv = *(const float4*)(wr + k);
            acc += wv.x * hx[k] + wv.y * hx[k + 1] + wv.z * hx[k + 2] + wv.w * hx[k + 3];
        }
        acc += __shfl_xor(acc, 1, 64);
        if (hf == 0) h2[row] = gelu_exact(acc + b2[row]);
    }
    __syncthreads();
    if (t < 64) {
        float v0 = h2[t], v1 = h2[64 + t];
        #pragma unroll
        for (int o = 0; o < 3; ++o) {
            float p = w3[o * 128 + t] * v0 + w3[o * 128 + 64 + t] * v1;
            #pragma unroll
            for (int off = 32; off >= 1; off >>= 1) p += __shfl_xor(p, off, 64);
            if (t == 0) out[which * (NG * 3) + g * 3 + o] = 1.f / (1.f + expf(-(p + b3[o])));
        }
    }
}

// ---------------------------------------------------------------- launch
extern "C" void kernel_launch(void* const* d_in, const int* in_sizes, int n_in, void* d_out,
                              int out_size, void* d_ws, size_t ws_size, hipStream_t stream) {
    const float* x         = (const float*)d_in[0];
    const int*   ei        = (const int*)d_in[1];
    const int*   src       = ei;
    const int*   dst       = ei + NE;
    const float* edge_attr = (const float*)d_in[2];
    const int*   batch     = (const int*)d_in[3];
    const float* node_w    = (const float*)d_in[4];
    const float* node_b    = (const float*)d_in[5];
    const float* eew       = (const float*)d_in[6];
    const float* eeb       = (const float*)d_in[7];
    const float* lin_w     = (const float*)d_in[8];
    const float* att_src   = (const float*)d_in[9];
    const float* att_dst   = (const float*)d_in[10];
    const float* att_edge  = (const float*)d_in[11];
    const float* lin_edge_w= (const float*)d_in[12];
    const float* conv_b    = (const float*)d_in[13];
    const float* ln_g      = (const float*)d_in[14];
    const float* ln_b      = (const float*)d_in[15];
    const float* pw1 = (const float*)d_in[16]; const float* pb1 = (const float*)d_in[17];
    const float* pw2 = (const float*)d_in[18]; const float* pb2 = (const float*)d_in[19];
    const float* pw3 = (const float*)d_in[20]; const float* pb3 = (const float*)d_in[21];
    const float* mw1 = (const float*)d_in[22]; const float* mb1 = (const float*)d_in[23];
    const float* mw2 = (const float*)d_in[24]; const float* mb2 = (const float*)d_in[25];
    const float* mw3 = (const float*)d_in[26]; const float* mb3 = (const float*)d_in[27];
    float* out = (float*)d_out;

    float* wsf = (float*)d_ws;
    float* hA        = wsf; wsf += (size_t)NN * HDIM;
    float* hB        = wsf; wsf += (size_t)NN * HDIM;
    float* preL      = wsf; wsf += (size_t)LAYERS * NN * 8;
    float* a_src     = wsf; wsf += (size_t)NN * HEADS;
    float* a_dst     = wsf; wsf += (size_t)NN * HEADS;
    float* bebuf     = wsf; wsf += 64;
    ushort* ubuf = (ushort*)wsf;
    ushort* ea_bf = ubuf; ubuf += (size_t)NE * EDGE_F;
    ushort* preEb = ubuf; ubuf += (size_t)NE * NOUT;   // [LAYERS][NE][8]
    ushort* webbf = ubuf; ubuf += (size_t)NOUT * EDGE_F;
    ushort* hhi  = ubuf; ubuf += (size_t)NN * HDIM;
    unsigned char* xwf8 = (unsigned char*)ubuf; ubuf += (size_t)NN * HDIM / 2;
    ushort* wbhi = ubuf; ubuf += (size_t)LAYERS * HDIM * HDIM;
    ushort* xhi  = ubuf; ubuf += (size_t)NN * NODE_F;
    ushort* nwhi = ubuf; ubuf += (size_t)HDIM * NODE_F;
    int* ibuf    = (int*)ubuf;
    int* cnt     = ibuf; ibuf += NN + 16;
    float* sums  = (float*)ibuf; ibuf += NG * HDIM;  // adjacent to cnt -> one memset
    int* row_ptr = ibuf; ibuf += NN + 16;
    int* pos     = ibuf; ibuf += NN + 16;
    int* csr_src = ibuf; ibuf += NE;

    // CSR build (+ permute edge_attr to CSR order, bf16); one memset covers cnt+sums
    hipMemsetAsync(cnt, 0, (NN + 16 + NG * HDIM) * sizeof(int), stream);
    count_kernel<<<(NE + 255) / 256, 256, 0, stream>>>(dst, cnt);
    scan_kernel<<<1, 1024, 0, stream>>>(cnt, row_ptr, pos);
    scatter_kernel<<<(NE + 255) / 256, 256, 0, stream>>>(src, dst, edge_attr, pos, csr_src,
                                                         ea_bf);

    // fold edge-attention weights (LOG2E-scaled); preE via MFMA; preL = mean over CSR range
    prep_kernel<<<LAYERS * HEADS, 256, 0, stream>>>(att_edge, lin_edge_w, eew, eeb, webbf, bebuf);
    preE_kernel<<<NE / 64, 256, 0, stream>>>(ea_bf, webbf, bebuf, preEb);
    preL_kernel<<<NN / 8, 256, 0, stream>>>(preEb, row_ptr, preL);

    // GEMM operand prep: everything bf16 (pure-bf16 GEMM), one fused conversion kernel
    {
        const int total = LAYERS * HDIM * HDIM + HDIM * NODE_F + NN * NODE_F;
        tobf_all_kernel<<<(total + 255) / 256, 256, 0, stream>>>(lin_w, node_w, x,
                                                                 wbhi, nwhi, xhi);
    }

    // node embedding: hhi = bf16(x @ node_w.T + node_b)  (layer 0 ignores h_prev -> no f32 out)
    {
        dim3 grid(HDIM / 64, (NN + 63) / 64);
        gemm_bf1<<<grid, 128, 0, stream>>>(xhi, nwhi, node_b, nullptr, hhi, nullptr,
                                           nullptr, nullptr, nullptr, nullptr,
                                           NN, NODE_F, HDIM);
    }

    float* cur = hA;
    float* nxt = hB;
    for (int i = 0; i < LAYERS; ++i) {
        dim3 grid(HDIM / 64, (NN + 63) / 64);
        // layer GEMM writes fp8 message table AND the fused a_src/a_dst epilogue
        gemm_bf1<<<grid, 128, 0, stream>>>(hhi, wbhi + (size_t)i * HDIM * HDIM, nullptr,
                                           nullptr, nullptr, xwf8,
                                           att_src + i * HEADS * 32, att_dst + i * HEADS * 32,
                                           a_src, a_dst, NN, HDIM, HDIM);
        node_kernel<<<NN / NPB, 64 * NPB, 0, stream>>>(
            xwf8, preEb + (size_t)i * NE * 8, preL + (size_t)i * NN * 8, a_src, a_dst,
            row_ptr, csr_src, cur, nxt, (i == LAYERS - 1) ? nullptr : hhi,
            conv_b + i * HDIM, ln_g + i * HDIM, ln_b + i * HDIM, i == 0 ? 1 : 0);
        float* tmp = cur; cur = nxt; nxt = tmp;
    }

    graph_sum_kernel<<<(NN + 63) / 64, 256, 0, stream>>>(cur, batch, sums);
    {
        dim3 gm(NG, 2);
        mlp_kernel<<<gm, 256, 0, stream>>>(sums, batch, pw1, pb1, pw2, pb2, pw3, pb3,
                                           mw1, mb1, mw2, mb2, mw3, mb3, out);
    }
}

// Round 3
// 524.423 us; speedup vs baseline: 1.1921x; 1.0345x over previous
//
#include <hip/hip_runtime.h>
#include <math.h>

#define NN 10000
#define NE 320000
#define NODE_F 64
#define EDGE_F 32
#define HDIM 256
#define HEADS 8
#define LAYERS 6
#define NG 16
#define NPB 2   // nodes per node_kernel block, ONE wave per node, no coupling
#define NOUT 48 // LAYERS*HEADS
#define LOG2E 1.4426950408889634f

typedef __attribute__((ext_vector_type(8))) short short8;
typedef __attribute__((ext_vector_type(4))) float float4v;
typedef __attribute__((ext_vector_type(2))) float floatx2;

// ---------------------------------------------------------------- CSR build
__global__ void count_kernel(const int* __restrict__ dst, int* __restrict__ cnt) {
    int e = blockIdx.x * 256 + threadIdx.x;
    if (e < NE) atomicAdd(&cnt[dst[e]], 1);
}

// shuffle-based scan: 1024 threads, 2 barriers total
__global__ void scan_kernel(const int* __restrict__ cnt, int* __restrict__ row_ptr,
                            int* __restrict__ pos) {
    __shared__ int wsum[16];
    __shared__ int woff[16];
    int t = threadIdx.x;
    int lane = t & 63, wid = t >> 6;
    const int chunk = 10;                 // 1024*10 >= NN
    int lo = t * chunk;
    int loc[10];
    int s = 0;
    #pragma unroll
    for (int k = 0; k < 10; ++k) {
        int i = lo + k;
        int v = (i < NN) ? cnt[i] : 0;
        loc[k] = v;
        s += v;
    }
    int inc = s;
    #pragma unroll
    for (int off = 1; off < 64; off <<= 1) {
        int v = __shfl_up(inc, off, 64);
        if (lane >= off) inc += v;
    }
    if (lane == 63) wsum[wid] = inc;
    __syncthreads();
    if (t < 16) {
        int inc2 = wsum[t];
        #pragma unroll
        for (int off = 1; off < 16; off <<= 1) {
            int u = __shfl_up(inc2, off, 16);
            if (t >= off) inc2 += u;
        }
        woff[t] = inc2;
    }
    __syncthreads();
    int base = inc - s + (wid ? woff[wid - 1] : 0);
    #pragma unroll
    for (int k = 0; k < 10; ++k) {
        int i = lo + k;
        if (i < NN) {
            row_ptr[i] = base;
            pos[i] = base;
            base += loc[k];
        }
    }
    if (t == 1023) row_ptr[NN] = woff[15];
}

// ---------------------------------------------------------------- bf16 helpers
__device__ __forceinline__ ushort f2bf(float f) {
    union { float f; unsigned u; } v; v.f = f;
    unsigned u = v.u;
    return (ushort)((u + 0x7fffu + ((u >> 16) & 1u)) >> 16);
}
__device__ __forceinline__ float bf2f(ushort b) {
    union { unsigned u; float f; } v; v.u = ((unsigned)b) << 16; return v.f;
}

// ---------------------------------------------------------------- edge-attn weight folding
// Fused fold + bf16 conversion, LOG2E-scaled so downstream softmax uses exp2.
__global__ __launch_bounds__(256) void prep_kernel(const float* __restrict__ att_edge,
                                                   const float* __restrict__ lin_edge_w,
                                                   const float* __restrict__ eew,
                                                   const float* __restrict__ eeb,
                                                   ushort* __restrict__ webbf,
                                                   float* __restrict__ bebuf) {
    int ih = blockIdx.x;            // i*HEADS + h
    int i = ih >> 3, h = ih & 7;
    __shared__ float vsh[HDIM];
    int t = threadIdx.x;
    float s = 0.f;
    const float* ae = att_edge + ih * 32;
    const float* lw = lin_edge_w + ((size_t)i * HDIM + h * 32) * HDIM + t;
    #pragma unroll
    for (int o = 0; o < 32; ++o) s += ae[o] * lw[(size_t)o * HDIM];
    vsh[t] = s;
    __syncthreads();
    if (t < EDGE_F) {
        float acc = 0.f;
        for (int k = 0; k < HDIM; ++k) acc += vsh[k] * eew[k * EDGE_F + t];
        webbf[ih * EDGE_F + t] = f2bf(acc * LOG2E);
    } else if (t == EDGE_F) {
        float acc = 0.f;
        for (int k = 0; k < HDIM; ++k) acc += vsh[k] * eeb[k];
        bebuf[ih] = acc * LOG2E;
    }
}

// ---------------------------------------------------------------- fused scatter + preE (MFMA)
// Gathers edge_attr (e-order, coalesced), converts to bf16 A-fragments, MFMAs
// against folded weights, and scatters 48 outputs per edge to its CSR slot
// preEb[li][idx][h] ([LAYERS][NE][8] bf16, LOG2E-scaled). csr_src written too.
__global__ __launch_bounds__(256) void scatterE_kernel(const int* __restrict__ src,
                                                       const int* __restrict__ dst,
                                                       const float* __restrict__ edge_attr,
                                                       int* __restrict__ pos,
                                                       int* __restrict__ csr_src,
                                                       const ushort* __restrict__ web,
                                                       const float* __restrict__ be,
                                                       ushort* __restrict__ preEb) {
    int wv = threadIdx.x >> 6, l = threadIdx.x & 63;
    int base = blockIdx.x * 64 + wv * 16;   // NE % 64 == 0
    int m = l & 15, kq = (l >> 4) * 8;
    // CSR scatter for these 16 edges by lanes 0..15
    int idxl = 0;
    if (l < 16) {
        int e = base + l;
        int d = dst[e];
        idxl = atomicAdd(&pos[d], 1);
        csr_src[idxl] = src[e];
    }
    // A fragment: edge row base+m, f32 -> bf16 in registers
    const float* ar = edge_attr + (size_t)(base + m) * EDGE_F + kq;
    float4 a0 = *(const float4*)(ar);
    float4 a1 = *(const float4*)(ar + 4);
    short8 afrag;
    afrag[0] = (short)f2bf(a0.x); afrag[1] = (short)f2bf(a0.y);
    afrag[2] = (short)f2bf(a0.z); afrag[3] = (short)f2bf(a0.w);
    afrag[4] = (short)f2bf(a1.x); afrag[5] = (short)f2bf(a1.y);
    afrag[6] = (short)f2bf(a1.z); afrag[7] = (short)f2bf(a1.w);
    float4v zero = {0.f, 0.f, 0.f, 0.f};
    float4v acc[3];
    #pragma unroll
    for (int ct = 0; ct < 3; ++ct) {
        short8 bfrag = *(const short8*)(web + (size_t)(ct * 16 + m) * EDGE_F + kq);
        acc[ct] = __builtin_amdgcn_mfma_f32_16x16x32_bf16(afrag, bfrag, zero, 0, 0, 0);
    }
    #pragma unroll
    for (int ct = 0; ct < 3; ++ct) {
        int oc = ct * 16 + m;
        int li = oc >> 3, hh = oc & 7;
        float bv = be[oc];
        #pragma unroll
        for (int r = 0; r < 4; ++r) {
            int row = (l >> 4) * 4 + r;
            int ridx = __shfl(idxl, row, 64);
            preEb[(size_t)li * NE * 8 + (size_t)ridx * 8 + hh] = f2bf(acc[ct][r] + bv);
        }
    }
}

// preL[l][n][h] = deg>0 ? mean over CSR range of preE : 0 — per-layer 16B contiguous reads
__global__ __launch_bounds__(256) void preL_kernel(const ushort* __restrict__ preEb,
                                                   const int* __restrict__ row_ptr,
                                                   float* __restrict__ preL) {
    int g = threadIdx.x >> 5, c = threadIdx.x & 31;
    int n = blockIdx.x * 8 + g;  // NN % 8 == 0
    int start = row_ptr[n], end = row_ptr[n + 1];
    int deg = end - start;
    float s[NOUT] = {};
    for (int idx = start + c; idx < end; idx += 32) {
        #pragma unroll
        for (int li = 0; li < LAYERS; ++li) {
            uint4 pk = *(const uint4*)(preEb + (size_t)li * NE * 8 + (size_t)idx * 8);
            s[li * 8 + 0] += bf2f((ushort)(pk.x & 0xffff));
            s[li * 8 + 1] += bf2f((ushort)(pk.x >> 16));
            s[li * 8 + 2] += bf2f((ushort)(pk.y & 0xffff));
            s[li * 8 + 3] += bf2f((ushort)(pk.y >> 16));
            s[li * 8 + 4] += bf2f((ushort)(pk.z & 0xffff));
            s[li * 8 + 5] += bf2f((ushort)(pk.z >> 16));
            s[li * 8 + 6] += bf2f((ushort)(pk.w & 0xffff));
            s[li * 8 + 7] += bf2f((ushort)(pk.w >> 16));
        }
    }
    #pragma unroll
    for (int off = 16; off >= 1; off >>= 1)
        #pragma unroll
        for (int h = 0; h < NOUT; ++h) s[h] += __shfl_xor(s[h], off, 32);
    if (c == 0) {
        float invd = deg > 0 ? 1.f / (float)deg : 0.f;
        for (int li = 0; li < LAYERS; ++li) {
            float4* dstp = (float4*)(preL + ((size_t)li * NN + n) * 8);
            dstp[0] = make_float4(s[li * 8 + 0] * invd, s[li * 8 + 1] * invd,
                                  s[li * 8 + 2] * invd, s[li * 8 + 3] * invd);
            dstp[1] = make_float4(s[li * 8 + 4] * invd, s[li * 8 + 5] * invd,
                                  s[li * 8 + 6] * invd, s[li * 8 + 7] * invd);
        }
    }
}

// ---------------------------------------------------------------- f32 -> bf16 (all three buffers)
__global__ void tobf_all_kernel(const float* __restrict__ lin_w, const float* __restrict__ node_w,
                                const float* __restrict__ x, ushort* __restrict__ wbhi,
                                ushort* __restrict__ nwhi, ushort* __restrict__ xhi) {
    const int N1 = LAYERS * HDIM * HDIM;   // 393216
    const int N2 = N1 + HDIM * NODE_F;     // 409600
    const int N3 = N2 + NN * NODE_F;       // 1049600
    int i = blockIdx.x * 256 + threadIdx.x;
    if (i < N1) wbhi[i] = f2bf(lin_w[i]);
    else if (i < N2) nwhi[i - N1] = f2bf(node_w[i - N1]);
    else if (i < N3) xhi[i - N2] = f2bf(x[i - N2]);
}

// ---------------------------------------------------------------- pure-bf16 MFMA GEMM
// C = A_bf . B_bf^T (+bias). Optional outputs: f32 C, bf16 Chi, fp8-e4m3 Cf8.
// If att_s != nullptr, also computes per-row attention logit partials a_src/a_dst
// (LOG2E-scaled) from the exact f32 accumulators — each 64-col block covers
// exactly 2 complete heads, so no atomics are needed.
__global__ __launch_bounds__(128) void gemm_bf1(const ushort* __restrict__ Ah,
                                                const ushort* __restrict__ Bh,
                                                const float* __restrict__ bias,
                                                float* __restrict__ C,
                                                ushort* __restrict__ Chi,
                                                unsigned char* __restrict__ Cf8,
                                                const float* __restrict__ att_s,
                                                const float* __restrict__ att_d,
                                                float* __restrict__ a_src,
                                                float* __restrict__ a_dst,
                                                int N, int K, int J) {
    __shared__ ushort sAh[64][40], sBh[64][40];
    int nb = blockIdx.y * 64, jb = blockIdx.x * 64;
    int t = threadIdx.x, w = t >> 6, l = t & 63;
    int srow = t >> 1, sq = (t & 1) * 16;
    int fr = l & 15, fq = (l >> 4) * 8;
    float4v acc[2][4] = {};
    for (int kt = 0; kt < K; kt += 32) {
        int gr = nb + srow;
        short8 a0 = {0,0,0,0,0,0,0,0}, a1 = {0,0,0,0,0,0,0,0};
        if (gr < N) {
            const short8* pa = (const short8*)(Ah + (size_t)gr * K + kt + sq);
            a0 = pa[0]; a1 = pa[1];
        }
        *(short8*)&sAh[srow][sq] = a0; *(short8*)&sAh[srow][sq + 8] = a1;
        const short8* pb = (const short8*)(Bh + (size_t)(jb + srow) * K + kt + sq);
        short8 b0 = pb[0], b1 = pb[1];
        *(short8*)&sBh[srow][sq] = b0; *(short8*)&sBh[srow][sq + 8] = b1;
        __syncthreads();
        short8 bh[4];
        #pragma unroll
        for (int nt = 0; nt < 4; ++nt)
            bh[nt] = *(const short8*)&sBh[nt * 16 + fr][fq];
        #pragma unroll
        for (int mt = 0; mt < 2; ++mt) {
            short8 ah = *(const short8*)&sAh[w * 32 + mt * 16 + fr][fq];
            #pragma unroll
            for (int nt = 0; nt < 4; ++nt)
                acc[mt][nt] = __builtin_amdgcn_mfma_f32_16x16x32_bf16(ah, bh[nt], acc[mt][nt], 0, 0, 0);
        }
        __syncthreads();
    }
    #pragma unroll
    for (int mt = 0; mt < 2; ++mt) {
        #pragma unroll
        for (int nt = 0; nt < 4; ++nt) {
            int col = jb + nt * 16 + fr;
            float bv = bias ? bias[col] : 0.f;
            #pragma unroll
            for (int r = 0; r < 4; ++r) {
                int row = nb + w * 32 + mt * 16 + (l >> 4) * 4 + r;
                if (row < N) {
                    float v = acc[mt][nt][r] + bv;
                    if (C) C[(size_t)row * J + col] = v;
                    if (Chi) Chi[(size_t)row * J + col] = f2bf(v);
                    if (Cf8) {
                        int pk8 = __builtin_amdgcn_cvt_pk_fp8_f32(v, v, 0, false);
                        Cf8[(size_t)row * J + col] = (unsigned char)(pk8 & 0xff);
                    }
                }
            }
        }
    }
    if (att_s) {
        int head0 = jb >> 5;
        float cs[4], cd[4];
        #pragma unroll
        for (int nt = 0; nt < 4; ++nt) {
            cs[nt] = att_s[jb + nt * 16 + fr] * LOG2E;
            cd[nt] = att_d[jb + nt * 16 + fr] * LOG2E;
        }
        #pragma unroll
        for (int mt = 0; mt < 2; ++mt) {
            #pragma unroll
            for (int r = 0; r < 4; ++r) {
                float s0 = acc[mt][0][r] * cs[0] + acc[mt][1][r] * cs[1];
                float s1 = acc[mt][2][r] * cs[2] + acc[mt][3][r] * cs[3];
                float d0 = acc[mt][0][r] * cd[0] + acc[mt][1][r] * cd[1];
                float d1 = acc[mt][2][r] * cd[2] + acc[mt][3][r] * cd[3];
                #pragma unroll
                for (int off = 8; off >= 1; off >>= 1) {
                    s0 += __shfl_xor(s0, off, 16);
                    s1 += __shfl_xor(s1, off, 16);
                    d0 += __shfl_xor(d0, off, 16);
                    d1 += __shfl_xor(d1, off, 16);
                }
                if (fr == 0) {
                    int row = nb + w * 32 + mt * 16 + (l >> 4) * 4 + r;
                    if (row < N) {
                        a_src[row * 8 + head0]     = s0;
                        a_src[row * 8 + head0 + 1] = s1;
                        a_dst[row * 8 + head0]     = d0;
                        a_dst[row * 8 + head0 + 1] = d1;
                    }
                }
            }
        }
    }
}

__device__ __forceinline__ float gelu_exact(float x) {
    return 0.5f * x * (1.f + erff(x * 0.70710678118654752f));
}

// ---------------------------------------------------------------- fused single-pass node kernel
// fp8-e4m3 message table (L2-resident), transposed logit computation: lane l
// computes the attention weight for (head l>>3, edge l&7) once, then the 64
// distinct (head,edge) weights are broadcast with __shfl — 3x fewer VMEM ops
// and ~4x fewer logit VALU ops than the per-lane-redundant scheme.
__global__ __launch_bounds__(64 * NPB) void node_kernel(const unsigned char* __restrict__ xwf8,
                                                  const ushort* __restrict__ pb,
                                                  const float* __restrict__ preL,
                                                  const float* __restrict__ a_src,
                                                  const float* __restrict__ a_dst,
                                                  const int* __restrict__ row_ptr,
                                                  const int* __restrict__ csr_src,
                                                  const float* __restrict__ h_prev,
                                                  float* __restrict__ h_next,
                                                  ushort* __restrict__ hhi,
                                                  const float* __restrict__ cb,
                                                  const float* __restrict__ lg,
                                                  const float* __restrict__ lb, int first) {
    int wv = threadIdx.x >> 6, l = threadIdx.x & 63;
    int n = blockIdx.x * NPB + wv;
    int start = row_ptr[n], end = row_ptr[n + 1];
    int hc = l >> 3;
    int hc8 = l & 56;
    int jj = l & 7;
    float adnh = a_dst[n * 8 + hc];
    const unsigned char* xb = xwf8 + 4 * l;

    float den, acc[4];
    {
        float al = a_src[n * 8 + hc] + adnh + preL[n * 8 + hc];
        al = fminf(fmaxf(al, 0.2f * al), 57.7f);
        float wself = exp2f(al);
        den = wself;
        unsigned gs = *(const unsigned*)(xb + (size_t)n * HDIM);
        floatx2 lo = __builtin_amdgcn_cvt_pk_f32_fp8(gs, false);
        floatx2 hi = __builtin_amdgcn_cvt_pk_f32_fp8(gs, true);
        acc[0] = wself * lo.x;
        acc[1] = wself * lo.y;
        acc[2] = wself * hi.x;
        acc[3] = wself * hi.y;
    }
    int idx = start;
    for (; idx + 8 <= end; idx += 8) {
        int sn[8];
        #pragma unroll
        for (int j = 0; j < 8; ++j) sn[j] = csr_src[idx + j];
        // this lane's (head, edge) logit
        int sn_t = csr_src[idx + jj];
        float p_t = bf2f(pb[(size_t)(idx + jj) * 8 + hc]);
        float a_t = a_src[(size_t)sn_t * 8 + hc] + adnh + p_t;
        float w_t = exp2f(fminf(fmaxf(a_t, 0.2f * a_t), 57.7f));
        unsigned g[8];
        #pragma unroll
        for (int j = 0; j < 8; ++j) g[j] = *(const unsigned*)(xb + (size_t)sn[j] * HDIM);
        #pragma unroll
        for (int j = 0; j < 8; ++j) {
            float wj = __shfl(w_t, hc8 + j, 64);
            floatx2 lo = __builtin_amdgcn_cvt_pk_f32_fp8(g[j], false);
            floatx2 hi = __builtin_amdgcn_cvt_pk_f32_fp8(g[j], true);
            den += wj;
            acc[0] += wj * lo.x;
            acc[1] += wj * lo.y;
            acc[2] += wj * hi.x;
            acc[3] += wj * hi.y;
        }
    }
    for (; idx < end; ++idx) {
        int sn = csr_src[idx];
        unsigned g = *(const unsigned*)(xb + (size_t)sn * HDIM);
        float a = a_src[(size_t)sn * 8 + hc] + adnh + bf2f(pb[(size_t)idx * 8 + hc]);
        float wt = exp2f(fminf(fmaxf(a, 0.2f * a), 57.7f));
        floatx2 lo = __builtin_amdgcn_cvt_pk_f32_fp8(g, false);
        floatx2 hi = __builtin_amdgcn_cvt_pk_f32_fp8(g, true);
        den += wt;
        acc[0] += wt * lo.x;
        acc[1] += wt * lo.y;
        acc[2] += wt * hi.x;
        acc[3] += wt * hi.y;
    }
    float4 cb4 = *(const float4*)(cb + 4 * l);
    float invh = 1.f / (den + 1e-16f);
    acc[0] = acc[0] * invh + cb4.x;
    acc[1] = acc[1] * invh + cb4.y;
    acc[2] = acc[2] * invh + cb4.z;
    acc[3] = acc[3] * invh + cb4.w;

    // LayerNorm over 256 channels
    float part = acc[0] + acc[1] + acc[2] + acc[3];
    #pragma unroll
    for (int off = 32; off >= 1; off >>= 1) part += __shfl_xor(part, off, 64);
    float mu = part * (1.f / 256.f);
    float p2 = 0.f;
    #pragma unroll
    for (int j = 0; j < 4; ++j) {
        float d = acc[j] - mu;
        p2 += d * d;
    }
    #pragma unroll
    for (int off = 32; off >= 1; off >>= 1) p2 += __shfl_xor(p2, off, 64);
    float rstd = rsqrtf(p2 * (1.f / 256.f) + 1e-5f);

    float4 lg4 = *(const float4*)(lg + 4 * l);
    float4 lb4 = *(const float4*)(lb + 4 * l);
    float o4[4];
    float lgv[4] = {lg4.x, lg4.y, lg4.z, lg4.w};
    float lbv[4] = {lb4.x, lb4.y, lb4.z, lb4.w};
    float4 hp = make_float4(0.f, 0.f, 0.f, 0.f);
    if (!first) hp = *(const float4*)(h_prev + (size_t)n * HDIM + 4 * l);
    float hpv[4] = {hp.x, hp.y, hp.z, hp.w};
    #pragma unroll
    for (int j = 0; j < 4; ++j) {
        float y = (acc[j] - mu) * rstd * lgv[j] + lbv[j];
        o4[j] = gelu_exact(y) + hpv[j];
    }
    *(float4*)(h_next + (size_t)n * HDIM + 4 * l) = make_float4(o4[0], o4[1], o4[2], o4[3]);
    if (hhi) {
        uint2 ph;
        ph.x = (unsigned)f2bf(o4[0]) | ((unsigned)f2bf(o4[1]) << 16);
        ph.y = (unsigned)f2bf(o4[2]) | ((unsigned)f2bf(o4[3]) << 16);
        *(uint2*)(hhi + (size_t)n * HDIM + 4 * l) = ph;
    }
}

// ---------------------------------------------------------------- graph readout
__global__ __launch_bounds__(256) void graph_sum_kernel(const float* __restrict__ h,
                                                        const int* __restrict__ batch,
                                                        float* __restrict__ sums) {
    int t = threadIdx.x;
    int n0 = blockIdx.x * 64;
    int n1 = min(NN, n0 + 64);
    float acc = 0.f;
    int cur = batch[n0];
    for (int n = n0; n < n1; ++n) {
        int b = batch[n];
        if (b != cur) {
            atomicAdd(&sums[cur * HDIM + t], acc);
            acc = 0.f;
            cur = b;
        }
        acc += h[(size_t)n * HDIM + t];
    }
    atomicAdd(&sums[cur * HDIM + t], acc);
}

__device__ __forceinline__ int lower_bound_dev(const int* a, int n, int v) {
    int lo = 0, hi = n;
    while (lo < hi) {
        int mid = (lo + hi) >> 1;
        if (a[mid] < v) lo = mid + 1; else hi = mid;
    }
    return lo;
}

// fused 3-layer MLP head: one block per (graph, which)
__global__ __launch_bounds__(256) void mlp_kernel(const float* __restrict__ sums,
                                                  const int* __restrict__ batch,
                                                  const float* __restrict__ pw1,
                                                  const float* __restrict__ pb1,
                                                  const float* __restrict__ pw2,
                                                  const float* __restrict__ pb2,
                                                  const float* __restrict__ pw3,
                                                  const float* __restrict__ pb3,
                                                  const float* __restrict__ mw1,
                                                  const float* __restrict__ mb1,
                                                  const float* __restrict__ mw2,
                                                  const float* __restrict__ mb2,
                                                  const float* __restrict__ mw3,
                                                  const float* __restrict__ mb3,
                                                  float* __restrict__ out) {
    int g = blockIdx.x, which = blockIdx.y;
    const float* w1 = which ? mw1 : pw1; const float* b1 = which ? mb1 : pb1;
    const float* w2 = which ? mw2 : pw2; const float* b2 = which ? mb2 : pb2;
    const float* w3 = which ? mw3 : pw3; const float* b3 = which ? mb3 : pb3;
    __shared__ float xg[512];
    __shared__ float h1[256];
    __shared__ float h2[128];
    __shared__ float cinv_s;
    int t = threadIdx.x;
    if (t == 0) {
        int s0 = lower_bound_dev(batch, NN, g), s1 = lower_bound_dev(batch, NN, g + 1);
        cinv_s = 1.f / fmaxf((float)(s1 - s0), 1.f);
    }
    __syncthreads();
    float sv = sums[g * HDIM + t];
    xg[t] = sv * cinv_s;
    xg[256 + t] = sv;
    __syncthreads();
    {
        const float* wr = w1 + (size_t)t * 512;
        float acc = 0.f;
        #pragma unroll 8
        for (int k = 0; k < 512; k += 4) {
            float4 wv = *(const float4*)(wr + k);
            acc += wv.x * xg[k] + wv.y * xg[k + 1] + wv.z * xg[k + 2] + wv.w * xg[k + 3];
        }
        h1[t] = gelu_exact(acc + b1[t]);
    }
    __syncthreads();
    {
        int row = t >> 1, hf = t & 1;
        const float* wr = w2 + (size_t)row * 256 + hf * 128;
        const float* hx = h1 + hf * 128;
        float acc = 0.f;
        #pragma unroll 8
        for (int k = 0; k < 128; k += 4) {
            float4 wv = *(const float4*)(wr + k);
            acc += wv.x * hx[k] + wv.y * hx[k + 1] + wv.z * hx[k + 2] + wv.w * hx[k + 3];
        }
        acc += __shfl_xor(acc, 1, 64);
        if (hf == 0) h2[row] = gelu_exact(acc + b2[row]);
    }
    __syncthreads();
    if (t < 64) {
        float v0 = h2[t], v1 = h2[64 + t];
        #pragma unroll
        for (int o = 0; o < 3; ++o) {
            float p = w3[o * 128 + t] * v0 + w3[o * 128 + 64 + t] * v1;
            #pragma unroll
            for (int off = 32; off >= 1; off >>= 1) p += __shfl_xor(p, off, 64);
            if (t == 0) out[which * (NG * 3) + g * 3 + o] = 1.f / (1.f + expf(-(p + b3[o])));
        }
    }
}

// ---------------------------------------------------------------- launch
extern "C" void kernel_launch(void* const* d_in, const int* in_sizes, int n_in, void* d_out,
                              int out_size, void* d_ws, size_t ws_size, hipStream_t stream) {
    const float* x         = (const float*)d_in[0];
    const int*   ei        = (const int*)d_in[1];
    const int*   src       = ei;
    const int*   dst       = ei + NE;
    const float* edge_attr = (const float*)d_in[2];
    const int*   batch     = (const int*)d_in[3];
    const float* node_w    = (const float*)d_in[4];
    const float* node_b    = (const float*)d_in[5];
    const float* eew       = (const float*)d_in[6];
    const float* eeb       = (const float*)d_in[7];
    const float* lin_w     = (const float*)d_in[8];
    const float* att_src   = (const float*)d_in[9];
    const float* att_dst   = (const float*)d_in[10];
    const float* att_edge  = (const float*)d_in[11];
    const float* lin_edge_w= (const float*)d_in[12];
    const float* conv_b    = (const float*)d_in[13];
    const float* ln_g      = (const float*)d_in[14];
    const float* ln_b      = (const float*)d_in[15];
    const float* pw1 = (const float*)d_in[16]; const float* pb1 = (const float*)d_in[17];
    const float* pw2 = (const float*)d_in[18]; const float* pb2 = (const float*)d_in[19];
    const float* pw3 = (const float*)d_in[20]; const float* pb3 = (const float*)d_in[21];
    const float* mw1 = (const float*)d_in[22]; const float* mb1 = (const float*)d_in[23];
    const float* mw2 = (const float*)d_in[24]; const float* mb2 = (const float*)d_in[25];
    const float* mw3 = (const float*)d_in[26]; const float* mb3 = (const float*)d_in[27];
    float* out = (float*)d_out;

    float* wsf = (float*)d_ws;
    float* hA        = wsf; wsf += (size_t)NN * HDIM;
    float* hB        = wsf; wsf += (size_t)NN * HDIM;
    float* preL      = wsf; wsf += (size_t)LAYERS * NN * 8;
    float* a_src     = wsf; wsf += (size_t)NN * HEADS;
    float* a_dst     = wsf; wsf += (size_t)NN * HEADS;
    float* bebuf     = wsf; wsf += 64;
    ushort* ubuf = (ushort*)wsf;
    ushort* preEb = ubuf; ubuf += (size_t)NE * NOUT;   // [LAYERS][NE][8]
    ushort* webbf = ubuf; ubuf += (size_t)NOUT * EDGE_F;
    ushort* hhi  = ubuf; ubuf += (size_t)NN * HDIM;
    unsigned char* xwf8 = (unsigned char*)ubuf; ubuf += (size_t)NN * HDIM / 2;
    ushort* wbhi = ubuf; ubuf += (size_t)LAYERS * HDIM * HDIM;
    ushort* xhi  = ubuf; ubuf += (size_t)NN * NODE_F;
    ushort* nwhi = ubuf; ubuf += (size_t)HDIM * NODE_F;
    int* ibuf    = (int*)ubuf;
    int* cnt     = ibuf; ibuf += NN + 16;
    float* sums  = (float*)ibuf; ibuf += NG * HDIM;  // adjacent to cnt -> one memset
    int* row_ptr = ibuf; ibuf += NN + 16;
    int* pos     = ibuf; ibuf += NN + 16;
    int* csr_src = ibuf; ibuf += NE;

    // CSR build; one memset covers cnt+sums
    hipMemsetAsync(cnt, 0, (NN + 16 + NG * HDIM) * sizeof(int), stream);
    count_kernel<<<(NE + 255) / 256, 256, 0, stream>>>(dst, cnt);
    scan_kernel<<<1, 1024, 0, stream>>>(cnt, row_ptr, pos);

    // fold edge-attention weights (LOG2E-scaled), then fused scatter+preE (MFMA),
    // then preL = mean over CSR range
    prep_kernel<<<LAYERS * HEADS, 256, 0, stream>>>(att_edge, lin_edge_w, eew, eeb, webbf, bebuf);
    scatterE_kernel<<<NE / 64, 256, 0, stream>>>(src, dst, edge_attr, pos, csr_src,
                                                 webbf, bebuf, preEb);
    preL_kernel<<<NN / 8, 256, 0, stream>>>(preEb, row_ptr, preL);

    // GEMM operand prep: everything bf16 (pure-bf16 GEMM), one fused conversion kernel
    {
        const int total = LAYERS * HDIM * HDIM + HDIM * NODE_F + NN * NODE_F;
        tobf_all_kernel<<<(total + 255) / 256, 256, 0, stream>>>(lin_w, node_w, x,
                                                                 wbhi, nwhi, xhi);
    }

    // node embedding: hhi = bf16(x @ node_w.T + node_b)  (layer 0 ignores h_prev -> no f32 out)
    {
        dim3 grid(HDIM / 64, (NN + 63) / 64);
        gemm_bf1<<<grid, 128, 0, stream>>>(xhi, nwhi, node_b, nullptr, hhi, nullptr,
                                           nullptr, nullptr, nullptr, nullptr,
                                           NN, NODE_F, HDIM);
    }

    float* cur = hA;
    float* nxt = hB;
    for (int i = 0; i < LAYERS; ++i) {
        dim3 grid(HDIM / 64, (NN + 63) / 64);
        // layer GEMM writes fp8 message table AND the fused a_src/a_dst epilogue
        gemm_bf1<<<grid, 128, 0, stream>>>(hhi, wbhi + (size_t)i * HDIM * HDIM, nullptr,
                                           nullptr, nullptr, xwf8,
                                           att_src + i * HEADS * 32, att_dst + i * HEADS * 32,
                                           a_src, a_dst, NN, HDIM, HDIM);
        node_kernel<<<NN / NPB, 64 * NPB, 0, stream>>>(
            xwf8, preEb + (size_t)i * NE * 8, preL + (size_t)i * NN * 8, a_src, a_dst,
            row_ptr, csr_src, cur, nxt, (i == LAYERS - 1) ? nullptr : hhi,
            conv_b + i * HDIM, ln_g + i * HDIM, ln_b + i * HDIM, i == 0 ? 1 : 0);
        float* tmp = cur; cur = nxt; nxt = tmp;
    }

    graph_sum_kernel<<<(NN + 63) / 64, 256, 0, stream>>>(cur, batch, sums);
    {
        dim3 gm(NG, 2);
        mlp_kernel<<<gm, 256, 0, stream>>>(sums, batch, pw1, pb1, pw2, pb2, pw3, pb3,
                                           mw1, mb1, mw2, mb2, mw3, mb3, out);
    }
}

// Round 5
// 509.119 us; speedup vs baseline: 1.2279x; 1.0301x over previous
//
#include <hip/hip_runtime.h>
#include <math.h>

#define NN 10000
#define NE 320000
#define NODE_F 64
#define EDGE_F 32
#define HDIM 256
#define HEADS 8
#define LAYERS 6
#define NG 16
#define NPB 2   // nodes per node_kernel block, ONE wave per node, no coupling
#define NOUT 48 // LAYERS*HEADS
#define LOG2E 1.4426950408889634f

typedef __attribute__((ext_vector_type(8))) short short8;
typedef __attribute__((ext_vector_type(4))) float float4v;
typedef __attribute__((ext_vector_type(2))) float floatx2;

// ---------------------------------------------------------------- CSR build
__global__ void count_kernel(const int* __restrict__ dst, int* __restrict__ cnt) {
    int e = blockIdx.x * 256 + threadIdx.x;
    if (e < NE) atomicAdd(&cnt[dst[e]], 1);
}

// shuffle-based scan: 1024 threads, 2 barriers total
__global__ void scan_kernel(const int* __restrict__ cnt, int* __restrict__ row_ptr,
                            int* __restrict__ pos) {
    __shared__ int wsum[16];
    __shared__ int woff[16];
    int t = threadIdx.x;
    int lane = t & 63, wid = t >> 6;
    const int chunk = 10;                 // 1024*10 >= NN
    int lo = t * chunk;
    int loc[10];
    int s = 0;
    #pragma unroll
    for (int k = 0; k < 10; ++k) {
        int i = lo + k;
        int v = (i < NN) ? cnt[i] : 0;
        loc[k] = v;
        s += v;
    }
    int inc = s;
    #pragma unroll
    for (int off = 1; off < 64; off <<= 1) {
        int v = __shfl_up(inc, off, 64);
        if (lane >= off) inc += v;
    }
    if (lane == 63) wsum[wid] = inc;
    __syncthreads();
    if (t < 16) {
        int inc2 = wsum[t];
        #pragma unroll
        for (int off = 1; off < 16; off <<= 1) {
            int u = __shfl_up(inc2, off, 16);
            if (t >= off) inc2 += u;
        }
        woff[t] = inc2;
    }
    __syncthreads();
    int base = inc - s + (wid ? woff[wid - 1] : 0);
    #pragma unroll
    for (int k = 0; k < 10; ++k) {
        int i = lo + k;
        if (i < NN) {
            row_ptr[i] = base;
            pos[i] = base;
            base += loc[k];
        }
    }
    if (t == 1023) row_ptr[NN] = woff[15];
}

// index-only CSR scatter: csr_se[idx] = {src[e], e}. 8B random writes into a
// 2.56 MB (L2-resident) buffer — payloads are NOT permuted.
__global__ void scatter_kernel(const int* __restrict__ src, const int* __restrict__ dst,
                               int* __restrict__ pos, int2* __restrict__ csr_se) {
    int e = blockIdx.x * 256 + threadIdx.x;
    if (e >= NE) return;
    int d = dst[e];
    int idx = atomicAdd(&pos[d], 1);
    csr_se[idx] = make_int2(src[e], e);
}

// ---------------------------------------------------------------- bf16 helpers
__device__ __forceinline__ ushort f2bf(float f) {
    union { float f; unsigned u; } v; v.f = f;
    unsigned u = v.u;
    return (ushort)((u + 0x7fffu + ((u >> 16) & 1u)) >> 16);
}
__device__ __forceinline__ float bf2f(ushort b) {
    union { unsigned u; float f; } v; v.u = ((unsigned)b) << 16; return v.f;
}

// ---------------------------------------------------------------- edge-attn weight folding
// Fused fold + bf16 conversion, LOG2E-scaled so downstream softmax uses exp2.
__global__ __launch_bounds__(256) void prep_kernel(const float* __restrict__ att_edge,
                                                   const float* __restrict__ lin_edge_w,
                                                   const float* __restrict__ eew,
                                                   const float* __restrict__ eeb,
                                                   ushort* __restrict__ webbf,
                                                   float* __restrict__ bebuf) {
    int ih = blockIdx.x;            // i*HEADS + h
    int i = ih >> 3, h = ih & 7;
    __shared__ float vsh[HDIM];
    int t = threadIdx.x;
    float s = 0.f;
    const float* ae = att_edge + ih * 32;
    const float* lw = lin_edge_w + ((size_t)i * HDIM + h * 32) * HDIM + t;
    #pragma unroll
    for (int o = 0; o < 32; ++o) s += ae[o] * lw[(size_t)o * HDIM];
    vsh[t] = s;
    __syncthreads();
    if (t < EDGE_F) {
        float acc = 0.f;
        for (int k = 0; k < HDIM; ++k) acc += vsh[k] * eew[k * EDGE_F + t];
        webbf[ih * EDGE_F + t] = f2bf(acc * LOG2E);
    } else if (t == EDGE_F) {
        float acc = 0.f;
        for (int k = 0; k < HDIM; ++k) acc += vsh[k] * eeb[k];
        bebuf[ih] = acc * LOG2E;
    }
}

// ---------------------------------------------------------------- preE via MFMA
// Pure streaming: read edge_attr in e-order (coalesced f32), write
// preEb[li][e][8] sequentially ([LAYERS][NE][8] bf16, LOG2E-scaled).
__global__ __launch_bounds__(256) void preE_kernel(const float* __restrict__ edge_attr,
                                                   const ushort* __restrict__ web,
                                                   const float* __restrict__ be,
                                                   ushort* __restrict__ preEb) {
    int wv = threadIdx.x >> 6, l = threadIdx.x & 63;
    int base = blockIdx.x * 64 + wv * 16;   // NE % 64 == 0
    int m = l & 15, kq = (l >> 4) * 8;
    const float* ar = edge_attr + (size_t)(base + m) * EDGE_F + kq;
    float4 a0 = *(const float4*)(ar);
    float4 a1 = *(const float4*)(ar + 4);
    short8 afrag;
    afrag[0] = (short)f2bf(a0.x); afrag[1] = (short)f2bf(a0.y);
    afrag[2] = (short)f2bf(a0.z); afrag[3] = (short)f2bf(a0.w);
    afrag[4] = (short)f2bf(a1.x); afrag[5] = (short)f2bf(a1.y);
    afrag[6] = (short)f2bf(a1.z); afrag[7] = (short)f2bf(a1.w);
    float4v zero = {0.f, 0.f, 0.f, 0.f};
    float4v acc[3];
    #pragma unroll
    for (int ct = 0; ct < 3; ++ct) {
        short8 bfrag = *(const short8*)(web + (size_t)(ct * 16 + m) * EDGE_F + kq);
        acc[ct] = __builtin_amdgcn_mfma_f32_16x16x32_bf16(afrag, bfrag, zero, 0, 0, 0);
    }
    #pragma unroll
    for (int ct = 0; ct < 3; ++ct) {
        int oc = ct * 16 + m;
        int li = oc >> 3, hh = oc & 7;
        float bv = be[oc];
        #pragma unroll
        for (int r = 0; r < 4; ++r) {
            int row = (l >> 4) * 4 + r;
            preEb[(size_t)li * NE * 8 + (size_t)(base + row) * 8 + hh] = f2bf(acc[ct][r] + bv);
        }
    }
}

// ---------------------------------------------------------------- f32 -> bf16 (all three buffers)
__global__ void tobf_all_kernel(const float* __restrict__ lin_w, const float* __restrict__ node_w,
                                const float* __restrict__ x, ushort* __restrict__ wbhi,
                                ushort* __restrict__ nwhi, ushort* __restrict__ xhi) {
    const int N1 = LAYERS * HDIM * HDIM;   // 393216
    const int N2 = N1 + HDIM * NODE_F;     // 409600
    const int N3 = N2 + NN * NODE_F;       // 1049600
    int i = blockIdx.x * 256 + threadIdx.x;
    if (i < N1) wbhi[i] = f2bf(lin_w[i]);
    else if (i < N2) nwhi[i - N1] = f2bf(node_w[i - N1]);
    else if (i < N3) xhi[i - N2] = f2bf(x[i - N2]);
}

// ---------------------------------------------------------------- pure-bf16 MFMA GEMM
// C = A_bf . B_bf^T (+bias). Optional outputs: f32 C, bf16 Chi, fp8-e4m3 Cf8.
// If att_s != nullptr, also computes per-row attention logit partials a_src/a_dst
// (LOG2E-scaled) from the exact f32 accumulators — each 64-col block covers
// exactly 2 complete heads, so no atomics are needed.
__global__ __launch_bounds__(128) void gemm_bf1(const ushort* __restrict__ Ah,
                                                const ushort* __restrict__ Bh,
                                                const float* __restrict__ bias,
                                                float* __restrict__ C,
                                                ushort* __restrict__ Chi,
                                                unsigned char* __restrict__ Cf8,
                                                const float* __restrict__ att_s,
                                                const float* __restrict__ att_d,
                                                float* __restrict__ a_src,
                                                float* __restrict__ a_dst,
                                                int N, int K, int J) {
    __shared__ ushort sAh[64][40], sBh[64][40];
    int nb = blockIdx.y * 64, jb = blockIdx.x * 64;
    int t = threadIdx.x, w = t >> 6, l = t & 63;
    int srow = t >> 1, sq = (t & 1) * 16;
    int fr = l & 15, fq = (l >> 4) * 8;
    float4v acc[2][4] = {};
    for (int kt = 0; kt < K; kt += 32) {
        int gr = nb + srow;
        short8 a0 = {0,0,0,0,0,0,0,0}, a1 = {0,0,0,0,0,0,0,0};
        if (gr < N) {
            const short8* pa = (const short8*)(Ah + (size_t)gr * K + kt + sq);
            a0 = pa[0]; a1 = pa[1];
        }
        *(short8*)&sAh[srow][sq] = a0; *(short8*)&sAh[srow][sq + 8] = a1;
        const short8* pb = (const short8*)(Bh + (size_t)(jb + srow) * K + kt + sq);
        short8 b0 = pb[0], b1 = pb[1];
        *(short8*)&sBh[srow][sq] = b0; *(short8*)&sBh[srow][sq + 8] = b1;
        __syncthreads();
        short8 bh[4];
        #pragma unroll
        for (int nt = 0; nt < 4; ++nt)
            bh[nt] = *(const short8*)&sBh[nt * 16 + fr][fq];
        #pragma unroll
        for (int mt = 0; mt < 2; ++mt) {
            short8 ah = *(const short8*)&sAh[w * 32 + mt * 16 + fr][fq];
            #pragma unroll
            for (int nt = 0; nt < 4; ++nt)
                acc[mt][nt] = __builtin_amdgcn_mfma_f32_16x16x32_bf16(ah, bh[nt], acc[mt][nt], 0, 0, 0);
        }
        __syncthreads();
    }
    #pragma unroll
    for (int mt = 0; mt < 2; ++mt) {
        #pragma unroll
        for (int nt = 0; nt < 4; ++nt) {
            int col = jb + nt * 16 + fr;
            float bv = bias ? bias[col] : 0.f;
            #pragma unroll
            for (int r = 0; r < 4; ++r) {
                int row = nb + w * 32 + mt * 16 + (l >> 4) * 4 + r;
                if (row < N) {
                    float v = acc[mt][nt][r] + bv;
                    if (C) C[(size_t)row * J + col] = v;
                    if (Chi) Chi[(size_t)row * J + col] = f2bf(v);
                    if (Cf8) {
                        int pk8 = __builtin_amdgcn_cvt_pk_fp8_f32(v, v, 0, false);
                        Cf8[(size_t)row * J + col] = (unsigned char)(pk8 & 0xff);
                    }
                }
            }
        }
    }
    if (att_s) {
        int head0 = jb >> 5;
        float cs[4], cd[4];
        #pragma unroll
        for (int nt = 0; nt < 4; ++nt) {
            cs[nt] = att_s[jb + nt * 16 + fr] * LOG2E;
            cd[nt] = att_d[jb + nt * 16 + fr] * LOG2E;
        }
        #pragma unroll
        for (int mt = 0; mt < 2; ++mt) {
            #pragma unroll
            for (int r = 0; r < 4; ++r) {
                float s0 = acc[mt][0][r] * cs[0] + acc[mt][1][r] * cs[1];
                float s1 = acc[mt][2][r] * cs[2] + acc[mt][3][r] * cs[3];
                float d0 = acc[mt][0][r] * cd[0] + acc[mt][1][r] * cd[1];
                float d1 = acc[mt][2][r] * cd[2] + acc[mt][3][r] * cd[3];
                #pragma unroll
                for (int off = 8; off >= 1; off >>= 1) {
                    s0 += __shfl_xor(s0, off, 16);
                    s1 += __shfl_xor(s1, off, 16);
                    d0 += __shfl_xor(d0, off, 16);
                    d1 += __shfl_xor(d1, off, 16);
                }
                if (fr == 0) {
                    int row = nb + w * 32 + mt * 16 + (l >> 4) * 4 + r;
                    if (row < N) {
                        a_src[row * 8 + head0]     = s0;
                        a_src[row * 8 + head0 + 1] = s1;
                        a_dst[row * 8 + head0]     = d0;
                        a_dst[row * 8 + head0 + 1] = d1;
                    }
                }
            }
        }
    }
}

__device__ __forceinline__ float gelu_exact(float x) {
    return 0.5f * x * (1.f + erff(x * 0.70710678118654752f));
}

// ---------------------------------------------------------------- fused single-pass node kernel
// fp8-e4m3 message table (L2-resident), transposed logit computation (lane =
// one (head, edge-slot) pair), in-register preL (psum shfl-reduce over the 8
// lanes of each head), unified masked 8-wide loop (no tail), self-loop last.
__global__ __launch_bounds__(64 * NPB) void node_kernel(const unsigned char* __restrict__ xwf8,
                                                  const ushort* __restrict__ pb,
                                                  const float* __restrict__ a_src,
                                                  const float* __restrict__ a_dst,
                                                  const int* __restrict__ row_ptr,
                                                  const int2* __restrict__ csr_se,
                                                  const float* __restrict__ h_prev,
                                                  float* __restrict__ h_next,
                                                  ushort* __restrict__ hhi,
                                                  const float* __restrict__ cb,
                                                  const float* __restrict__ lg,
                                                  const float* __restrict__ lb, int first) {
    int wv = threadIdx.x >> 6, l = threadIdx.x & 63;
    int n = blockIdx.x * NPB + wv;
    int start = row_ptr[n], end = row_ptr[n + 1];
    int hc = l >> 3;
    int hc8 = l & 56;
    int jj = l & 7;
    float adnh = a_dst[n * 8 + hc];
    const unsigned char* xb = xwf8 + 4 * l;

    float den = 0.f, acc[4] = {0.f, 0.f, 0.f, 0.f};
    float psum = 0.f;
    for (int idx = start; idx < end; idx += 8) {
        int myi = idx + jj;
        bool valid = myi < end;
        int2 se = valid ? csr_se[myi] : make_int2(n, 0);
        int snj[8];
        #pragma unroll
        for (int j = 0; j < 8; ++j) snj[j] = __shfl(se.x, hc8 + j, 64);
        unsigned g[8];
        #pragma unroll
        for (int j = 0; j < 8; ++j) g[j] = *(const unsigned*)(xb + (size_t)snj[j] * HDIM);
        float w_t = 0.f;
        if (valid) {
            float p_t = bf2f(pb[(size_t)se.y * 8 + hc]);
            float a_t = a_src[(size_t)se.x * 8 + hc] + adnh + p_t;
            w_t = exp2f(fminf(fmaxf(a_t, 0.2f * a_t), 57.7f));
            psum += p_t;
        }
        #pragma unroll
        for (int j = 0; j < 8; ++j) {
            float wj = __shfl(w_t, hc8 + j, 64);
            floatx2 lo = __builtin_amdgcn_cvt_pk_f32_fp8(g[j], false);
            floatx2 hi = __builtin_amdgcn_cvt_pk_f32_fp8(g[j], true);
            den += wj;
            acc[0] += wj * lo.x;
            acc[1] += wj * lo.y;
            acc[2] += wj * hi.x;
            acc[3] += wj * hi.y;
        }
    }
    // in-register preL: mean of this head's p over incoming edges
    #pragma unroll
    for (int off = 1; off < 8; off <<= 1) psum += __shfl_xor(psum, off, 64);
    int deg = end - start;
    float preLv = deg > 0 ? psum / (float)deg : 0.f;
    // self loop
    {
        float al = a_src[n * 8 + hc] + adnh + preLv;
        al = fminf(fmaxf(al, 0.2f * al), 57.7f);
        float wself = exp2f(al);
        den += wself;
        unsigned gs = *(const unsigned*)(xb + (size_t)n * HDIM);
        floatx2 lo = __builtin_amdgcn_cvt_pk_f32_fp8(gs, false);
        floatx2 hi = __builtin_amdgcn_cvt_pk_f32_fp8(gs, true);
        acc[0] += wself * lo.x;
        acc[1] += wself * lo.y;
        acc[2] += wself * hi.x;
        acc[3] += wself * hi.y;
    }
    float4 cb4 = *(const float4*)(cb + 4 * l);
    float invh = 1.f / (den + 1e-16f);
    acc[0] = acc[0] * invh + cb4.x;
    acc[1] = acc[1] * invh + cb4.y;
    acc[2] = acc[2] * invh + cb4.z;
    acc[3] = acc[3] * invh + cb4.w;

    // LayerNorm over 256 channels
    float part = acc[0] + acc[1] + acc[2] + acc[3];
    #pragma unroll
    for (int off = 32; off >= 1; off >>= 1) part += __shfl_xor(part, off, 64);
    float mu = part * (1.f / 256.f);
    float p2 = 0.f;
    #pragma unroll
    for (int j = 0; j < 4; ++j) {
        float d = acc[j] - mu;
        p2 += d * d;
    }
    #pragma unroll
    for (int off = 32; off >= 1; off >>= 1) p2 += __shfl_xor(p2, off, 64);
    float rstd = rsqrtf(p2 * (1.f / 256.f) + 1e-5f);

    float4 lg4 = *(const float4*)(lg + 4 * l);
    float4 lb4 = *(const float4*)(lb + 4 * l);
    float o4[4];
    float lgv[4] = {lg4.x, lg4.y, lg4.z, lg4.w};
    float lbv[4] = {lb4.x, lb4.y, lb4.z, lb4.w};
    float4 hp = make_float4(0.f, 0.f, 0.f, 0.f);
    if (!first) hp = *(const float4*)(h_prev + (size_t)n * HDIM + 4 * l);
    float hpv[4] = {hp.x, hp.y, hp.z, hp.w};
    #pragma unroll
    for (int j = 0; j < 4; ++j) {
        float y = (acc[j] - mu) * rstd * lgv[j] + lbv[j];
        o4[j] = gelu_exact(y) + hpv[j];
    }
    *(float4*)(h_next + (size_t)n * HDIM + 4 * l) = make_float4(o4[0], o4[1], o4[2], o4[3]);
    if (hhi) {
        uint2 ph;
        ph.x = (unsigned)f2bf(o4[0]) | ((unsigned)f2bf(o4[1]) << 16);
        ph.y = (unsigned)f2bf(o4[2]) | ((unsigned)f2bf(o4[3]) << 16);
        *(uint2*)(hhi + (size_t)n * HDIM + 4 * l) = ph;
    }
}

// ---------------------------------------------------------------- graph readout
__global__ __launch_bounds__(256) void graph_sum_kernel(const float* __restrict__ h,
                                                        const int* __restrict__ batch,
                                                        float* __restrict__ sums) {
    int t = threadIdx.x;
    int n0 = blockIdx.x * 64;
    int n1 = min(NN, n0 + 64);
    float acc = 0.f;
    int cur = batch[n0];
    for (int n = n0; n < n1; ++n) {
        int b = batch[n];
        if (b != cur) {
            atomicAdd(&sums[cur * HDIM + t], acc);
            acc = 0.f;
            cur = b;
        }
        acc += h[(size_t)n * HDIM + t];
    }
    atomicAdd(&sums[cur * HDIM + t], acc);
}

__device__ __forceinline__ int lower_bound_dev(const int* a, int n, int v) {
    int lo = 0, hi = n;
    while (lo < hi) {
        int mid = (lo + hi) >> 1;
        if (a[mid] < v) lo = mid + 1; else hi = mid;
    }
    return lo;
}

// fused 3-layer MLP head: one block per (graph, which)
__global__ __launch_bounds__(256) void mlp_kernel(const float* __restrict__ sums,
                                                  const int* __restrict__ batch,
                                                  const float* __restrict__ pw1,
                                                  const float* __restrict__ pb1,
                                                  const float* __restrict__ pw2,
                                                  const float* __restrict__ pb2,
                                                  const float* __restrict__ pw3,
                                                  const float* __restrict__ pb3,
                                                  const float* __restrict__ mw1,
                                                  const float* __restrict__ mb1,
                                                  const float* __restrict__ mw2,
                                                  const float* __restrict__ mb2,
                                                  const float* __restrict__ mw3,
                                                  const float* __restrict__ mb3,
                                                  float* __restrict__ out) {
    int g = blockIdx.x, which = blockIdx.y;
    const float* w1 = which ? mw1 : pw1; const float* b1 = which ? mb1 : pb1;
    const float* w2 = which ? mw2 : pw2; const float* b2 = which ? mb2 : pb2;
    const float* w3 = which ? mw3 : pw3; const float* b3 = which ? mb3 : pb3;
    __shared__ float xg[512];
    __shared__ float h1[256];
    __shared__ float h2[128];
    __shared__ float cinv_s;
    int t = threadIdx.x;
    if (t == 0) {
        int s0 = lower_bound_dev(batch, NN, g), s1 = lower_bound_dev(batch, NN, g + 1);
        cinv_s = 1.f / fmaxf((float)(s1 - s0), 1.f);
    }
    __syncthreads();
    float sv = sums[g * HDIM + t];
    xg[t] = sv * cinv_s;
    xg[256 + t] = sv;
    __syncthreads();
    {
        const float* wr = w1 + (size_t)t * 512;
        float acc = 0.f;
        #pragma unroll 8
        for (int k = 0; k < 512; k += 4) {
            float4 wv = *(const float4*)(wr + k);
            acc += wv.x * xg[k] + wv.y * xg[k + 1] + wv.z * xg[k + 2] + wv.w * xg[k + 3];
        }
        h1[t] = gelu_exact(acc + b1[t]);
    }
    __syncthreads();
    {
        int row = t >> 1, hf = t & 1;
        const float* wr = w2 + (size_t)row * 256 + hf * 128;
        const float* hx = h1 + hf * 128;
        float acc = 0.f;
        #pragma unroll 8
        for (int k = 0; k < 128; k += 4) {
            float4 wv = *(const float4*)(wr + k);
            acc += wv.x * hx[k] + wv.y * hx[k + 1] + wv.z * hx[k + 2] + wv.w * hx[k + 3];
        }
        acc += __shfl_xor(acc, 1, 64);
        if (hf == 0) h2[row] = gelu_exact(acc + b2[row]);
    }
    __syncthreads();
    if (t < 64) {
        float v0 = h2[t], v1 = h2[64 + t];
        #pragma unroll
        for (int o = 0; o < 3; ++o) {
            float p = w3[o * 128 + t] * v0 + w3[o * 128 + 64 + t] * v1;
            #pragma unroll
            for (int off = 32; off >= 1; off >>= 1) p += __shfl_xor(p, off, 64);
            if (t == 0) out[which * (NG * 3) + g * 3 + o] = 1.f / (1.f + expf(-(p + b3[o])));
        }
    }
}

// ---------------------------------------------------------------- launch
extern "C" void kernel_launch(void* const* d_in, const int* in_sizes, int n_in, void* d_out,
                              int out_size, void* d_ws, size_t ws_size, hipStream_t stream) {
    const float* x         = (const float*)d_in[0];
    const int*   ei        = (const int*)d_in[1];
    const int*   src       = ei;
    const int*   dst       = ei + NE;
    const float* edge_attr = (const float*)d_in[2];
    const int*   batch     = (const int*)d_in[3];
    const float* node_w    = (const float*)d_in[4];
    const float* node_b    = (const float*)d_in[5];
    const float* eew       = (const float*)d_in[6];
    const float* eeb       = (const float*)d_in[7];
    const float* lin_w     = (const float*)d_in[8];
    const float* att_src   = (const float*)d_in[9];
    const float* att_dst   = (const float*)d_in[10];
    const float* att_edge  = (const float*)d_in[11];
    const float* lin_edge_w= (const float*)d_in[12];
    const float* conv_b    = (const float*)d_in[13];
    const float* ln_g      = (const float*)d_in[14];
    const float* ln_b      = (const float*)d_in[15];
    const float* pw1 = (const float*)d_in[16]; const float* pb1 = (const float*)d_in[17];
    const float* pw2 = (const float*)d_in[18]; const float* pb2 = (const float*)d_in[19];
    const float* pw3 = (const float*)d_in[20]; const float* pb3 = (const float*)d_in[21];
    const float* mw1 = (const float*)d_in[22]; const float* mb1 = (const float*)d_in[23];
    const float* mw2 = (const float*)d_in[24]; const float* mb2 = (const float*)d_in[25];
    const float* mw3 = (const float*)d_in[26]; const float* mb3 = (const float*)d_in[27];
    float* out = (float*)d_out;

    float* wsf = (float*)d_ws;
    float* hA        = wsf; wsf += (size_t)NN * HDIM;
    float* hB        = wsf; wsf += (size_t)NN * HDIM;
    float* a_src     = wsf; wsf += (size_t)NN * HEADS;
    float* a_dst     = wsf; wsf += (size_t)NN * HEADS;
    float* bebuf     = wsf; wsf += 64;
    ushort* ubuf = (ushort*)wsf;
    ushort* preEb = ubuf; ubuf += (size_t)NE * NOUT;   // [LAYERS][NE][8], e-order
    ushort* webbf = ubuf; ubuf += (size_t)NOUT * EDGE_F;
    ushort* hhi  = ubuf; ubuf += (size_t)NN * HDIM;
    unsigned char* xwf8 = (unsigned char*)ubuf; ubuf += (size_t)NN * HDIM / 2;
    ushort* wbhi = ubuf; ubuf += (size_t)LAYERS * HDIM * HDIM;
    ushort* xhi  = ubuf; ubuf += (size_t)NN * NODE_F;
    ushort* nwhi = ubuf; ubuf += (size_t)HDIM * NODE_F;
    int* ibuf    = (int*)ubuf;
    int* cnt     = ibuf; ibuf += NN + 16;
    float* sums  = (float*)ibuf; ibuf += NG * HDIM;  // adjacent to cnt -> one memset
    int* row_ptr = ibuf; ibuf += NN + 16;
    int* pos     = ibuf; ibuf += NN + 16;
    ibuf += (((size_t)ibuf & 4) ? 1 : 0);            // 8B-align csr_se
    int2* csr_se = (int2*)ibuf; ibuf += 2 * NE;

    // CSR build (index-only); one memset covers cnt+sums
    hipMemsetAsync(cnt, 0, (NN + 16 + NG * HDIM) * sizeof(int), stream);
    count_kernel<<<(NE + 255) / 256, 256, 0, stream>>>(dst, cnt);
    scan_kernel<<<1, 1024, 0, stream>>>(cnt, row_ptr, pos);
    scatter_kernel<<<(NE + 255) / 256, 256, 0, stream>>>(src, dst, pos, csr_se);

    // fold edge-attention weights (LOG2E-scaled); preE = pure streaming MFMA
    prep_kernel<<<LAYERS * HEADS, 256, 0, stream>>>(att_edge, lin_edge_w, eew, eeb, webbf, bebuf);
    preE_kernel<<<NE / 64, 256, 0, stream>>>(edge_attr, webbf, bebuf, preEb);

    // GEMM operand prep: everything bf16 (pure-bf16 GEMM), one fused conversion kernel
    {
        const int total = LAYERS * HDIM * HDIM + HDIM * NODE_F + NN * NODE_F;
        tobf_all_kernel<<<(total + 255) / 256, 256, 0, stream>>>(lin_w, node_w, x,
                                                                 wbhi, nwhi, xhi);
    }

    // node embedding: hhi = bf16(x @ node_w.T + node_b)
    {
        dim3 grid(HDIM / 64, (NN + 63) / 64);
        gemm_bf1<<<grid, 128, 0, stream>>>(xhi, nwhi, node_b, nullptr, hhi, nullptr,
                                           nullptr, nullptr, nullptr, nullptr,
                                           NN, NODE_F, HDIM);
    }

    float* cur = hA;
    float* nxt = hB;
    for (int i = 0; i < LAYERS; ++i) {
        dim3 grid(HDIM / 64, (NN + 63) / 64);
        // layer GEMM writes fp8 message table AND the fused a_src/a_dst epilogue
        gemm_bf1<<<grid, 128, 0, stream>>>(hhi, wbhi + (size_t)i * HDIM * HDIM, nullptr,
                                           nullptr, nullptr, xwf8,
                                           att_src + i * HEADS * 32, att_dst + i * HEADS * 32,
                                           a_src, a_dst, NN, HDIM, HDIM);
        node_kernel<<<NN / NPB, 64 * NPB, 0, stream>>>(
            xwf8, preEb + (size_t)i * NE * 8, a_src, a_dst,
            row_ptr, csr_se, cur, nxt, (i == LAYERS - 1) ? nullptr : hhi,
            conv_b + i * HDIM, ln_g + i * HDIM, ln_b + i * HDIM, i == 0 ? 1 : 0);
        float* tmp = cur; cur = nxt; nxt = tmp;
    }

    graph_sum_kernel<<<(NN + 63) / 64, 256, 0, stream>>>(cur, batch, sums);
    {
        dim3 gm(NG, 2);
        mlp_kernel<<<gm, 256, 0, stream>>>(sums, batch, pw1, pb1, pw2, pb2, pw3, pb3,
                                           mw1, mb1, mw2, mb2, mw3, mb3, out);
    }
}